// Round 1
// baseline (983.090 us; speedup 1.0000x reference)
//
#include <hip/hip_runtime.h>
#include <math.h>

#define N_NODES 100000
#define N_EDGES 1600000
#define F_INF   128
#define HIDF    128

// ---------------------------------------------------------------- edge MLP
// wave per edge (grid-stride): lane j covers hidden units j=lane and j=lane+64.
// All 1152+130 weights preloaded into per-lane VGPRs once per wave.
__global__ void k_edge_mlp(const float* __restrict__ ea,
                           const float* __restrict__ w1, const float* __restrict__ b1,
                           const float* __restrict__ w2, const float* __restrict__ b2,
                           float* __restrict__ ew) {
    const int lane   = threadIdx.x & 63;
    const int wid    = blockIdx.x * (blockDim.x >> 6) + (threadIdx.x >> 6);
    const int nwaves = gridDim.x * (blockDim.x >> 6);

    float w1a[8], w1b[8];
#pragma unroll
    for (int k = 0; k < 8; ++k) {
        w1a[k] = w1[k * 128 + lane];
        w1b[k] = w1[k * 128 + 64 + lane];
    }
    const float b1a = b1[lane], b1b = b1[64 + lane];
    const float w2a = w2[lane], w2b = w2[64 + lane];
    const float bias2 = b2[0];

    for (int e = wid; e < N_EDGES; e += nwaves) {
        const float4 a0 = *(const float4*)(ea + (size_t)e * 8);
        const float4 a1 = *(const float4*)(ea + (size_t)e * 8 + 4);
        float ha = b1a, hb = b1b;
        ha = fmaf(a0.x, w1a[0], ha); hb = fmaf(a0.x, w1b[0], hb);
        ha = fmaf(a0.y, w1a[1], ha); hb = fmaf(a0.y, w1b[1], hb);
        ha = fmaf(a0.z, w1a[2], ha); hb = fmaf(a0.z, w1b[2], hb);
        ha = fmaf(a0.w, w1a[3], ha); hb = fmaf(a0.w, w1b[3], hb);
        ha = fmaf(a1.x, w1a[4], ha); hb = fmaf(a1.x, w1b[4], hb);
        ha = fmaf(a1.y, w1a[5], ha); hb = fmaf(a1.y, w1b[5], hb);
        ha = fmaf(a1.z, w1a[6], ha); hb = fmaf(a1.z, w1b[6], hb);
        ha = fmaf(a1.w, w1a[7], ha); hb = fmaf(a1.w, w1b[7], hb);
        float p = fmaxf(ha, 0.f) * w2a + fmaxf(hb, 0.f) * w2b;
#pragma unroll
        for (int m = 1; m < 64; m <<= 1) p += __shfl_xor(p, m, 64);
        if (lane == 0) {
            float z = p + bias2;
            ew[e] = 1.f / (1.f + __expf(-z));
        }
    }
}

// ---------------------------------------------------------------- CSR build
__global__ void k_deg(const int* __restrict__ dst, int* __restrict__ deg) {
    int e = blockIdx.x * 256 + threadIdx.x;
    if (e < N_EDGES) atomicAdd(&deg[dst[e]], 1);
}

__global__ void k_scan1(const int* __restrict__ deg, int* __restrict__ incl,
                        int* __restrict__ bsum) {
    __shared__ int sm[1024];
    const int tid = threadIdx.x;
    const int gi  = blockIdx.x * 1024 + tid;
    int v = (gi < N_NODES) ? deg[gi] : 0;
    sm[tid] = v;
    __syncthreads();
    for (int off = 1; off < 1024; off <<= 1) {
        int t = (tid >= off) ? sm[tid - off] : 0;
        __syncthreads();
        sm[tid] += t;
        __syncthreads();
    }
    if (gi < N_NODES) incl[gi] = sm[tid];
    if (tid == 1023) bsum[blockIdx.x] = sm[1023];
}

__global__ void k_scan2(const int* __restrict__ bsum, int* __restrict__ boff, int nb) {
    __shared__ int sm[128];
    const int tid = threadIdx.x;  // 128 threads
    int v = (tid < nb) ? bsum[tid] : 0;
    sm[tid] = v;
    __syncthreads();
    for (int off = 1; off < 128; off <<= 1) {
        int t = (tid >= off) ? sm[tid - off] : 0;
        __syncthreads();
        sm[tid] += t;
        __syncthreads();
    }
    boff[tid] = sm[tid] - v;  // exclusive
}

__global__ void k_scan3(const int* __restrict__ incl, const int* __restrict__ boff,
                        int* __restrict__ rowptr) {
    int i = blockIdx.x * 256 + threadIdx.x;
    if (i < N_NODES) rowptr[i + 1] = boff[i >> 10] + incl[i];
    if (i == 0) rowptr[0] = 0;
}

__global__ void k_fill(const int* __restrict__ src, const int* __restrict__ dst,
                       const float* __restrict__ ew, const int* __restrict__ rowptr,
                       int* __restrict__ cursor, int* __restrict__ col,
                       float* __restrict__ wgt) {
    int e = blockIdx.x * 256 + threadIdx.x;
    if (e < N_EDGES) {
        int d   = dst[e];
        int pos = rowptr[d] + atomicAdd(&cursor[d], 1);
        col[pos] = src[e];
        wgt[pos] = ew[e];
    }
}

// ---------------------------------------------------------------- aggregation
// wave per node; lane covers feature cols {lane*2, lane*2+1}; each edge is one
// wave-coalesced 512B row gather. 4-wide unroll for MLP... for memory-level parallelism.
__global__ void k_agg(const float* __restrict__ xin, const int* __restrict__ rowptr,
                      const int* __restrict__ col, const float* __restrict__ wgt,
                      float* __restrict__ aggout) {
    const int lane = threadIdx.x & 63;
    const int node = blockIdx.x * (blockDim.x >> 6) + (threadIdx.x >> 6);
    if (node >= N_NODES) return;
    const int s = rowptr[node], e = rowptr[node + 1];
    float ax = 0.f, ay = 0.f;
    int j = s;
    for (; j + 4 <= e; j += 4) {
        int   s0 = col[j],   s1 = col[j + 1],  s2 = col[j + 2],  s3 = col[j + 3];
        float w0 = wgt[j],   w1 = wgt[j + 1],  w2 = wgt[j + 2],  w3 = wgt[j + 3];
        float2 v0 = *(const float2*)(xin + (size_t)s0 * 128 + lane * 2);
        float2 v1 = *(const float2*)(xin + (size_t)s1 * 128 + lane * 2);
        float2 v2 = *(const float2*)(xin + (size_t)s2 * 128 + lane * 2);
        float2 v3 = *(const float2*)(xin + (size_t)s3 * 128 + lane * 2);
        ax += w0 * v0.x + w1 * v1.x + w2 * v2.x + w3 * v3.x;
        ay += w0 * v0.y + w1 * v1.y + w2 * v2.y + w3 * v3.y;
    }
    for (; j < e; ++j) {
        int s0 = col[j]; float w0 = wgt[j];
        float2 v0 = *(const float2*)(xin + (size_t)s0 * 128 + lane * 2);
        ax += w0 * v0.x; ay += w0 * v0.y;
    }
    const float inv = 1.f / fmaxf((float)(e - s), 1.f);
    float2 r; r.x = ax * inv; r.y = ay * inv;
    *(float2*)(aggout + (size_t)node * 128 + lane * 2) = r;
}

// ---------------------------------------------------------------- fused GEMM
// h = relu(bn(agg@Wl + b_l + x@Wr)) as one K=256 GEMM.
// 128x128 block tile, 256 threads, 8 rows x 8 cols per thread (cols split c0 /
// c0+64 so LDS b128 reads alias banks only 2-way = free). W k-tile in LDS (32KB),
// A straight from global (16B loads broadcast to 16 lanes).
__global__ __launch_bounds__(256) void k_gemm_fused(
    const float* __restrict__ Aagg, const float* __restrict__ Ax,
    const float* __restrict__ Wl, const float* __restrict__ Wr,
    const float* __restrict__ bl,
    const float* __restrict__ bng, const float* __restrict__ bnb,
    const float* __restrict__ bnm, const float* __restrict__ bnv,
    float* __restrict__ out) {
    __shared__ float Ws[64 * 128];
    const int tid  = threadIdx.x;
    const int cg   = tid & 15;
    const int rg   = tid >> 4;
    const int row0 = blockIdx.x * 128 + rg * 8;
    const int c0   = cg * 4, c1 = 64 + cg * 4;

    int rows[8];
#pragma unroll
    for (int r = 0; r < 8; ++r) rows[r] = min(row0 + r, N_NODES - 1);

    float acc[8][8];
#pragma unroll
    for (int r = 0; r < 8; ++r)
#pragma unroll
        for (int q = 0; q < 8; ++q) acc[r][q] = 0.f;

    for (int kt = 0; kt < 4; ++kt) {
        const float* Wsrc  = (kt < 2) ? Wl : Wr;
        const float* Asrc  = (kt < 2) ? Aagg : Ax;
        const int    kbase = (kt & 1) * 64;
        // stage 64x128 W tile (contiguous slab)
#pragma unroll
        for (int i = 0; i < 8; ++i) {
            int fi = tid * 4 + i * 1024;
            *(float4*)(Ws + fi) = *(const float4*)(Wsrc + (size_t)kbase * 128 + fi);
        }
        __syncthreads();
#pragma unroll 2
        for (int k4 = 0; k4 < 64; k4 += 4) {
            float4 a[8];
#pragma unroll
            for (int r = 0; r < 8; ++r)
                a[r] = *(const float4*)(Asrc + (size_t)rows[r] * 128 + kbase + k4);
#pragma unroll
            for (int kk = 0; kk < 4; ++kk) {
                const float4 wA = *(const float4*)(Ws + (k4 + kk) * 128 + c0);
                const float4 wB = *(const float4*)(Ws + (k4 + kk) * 128 + c1);
#pragma unroll
                for (int r = 0; r < 8; ++r) {
                    float av = (kk == 0) ? a[r].x : (kk == 1) ? a[r].y
                              : (kk == 2) ? a[r].z : a[r].w;
                    acc[r][0] = fmaf(av, wA.x, acc[r][0]);
                    acc[r][1] = fmaf(av, wA.y, acc[r][1]);
                    acc[r][2] = fmaf(av, wA.z, acc[r][2]);
                    acc[r][3] = fmaf(av, wA.w, acc[r][3]);
                    acc[r][4] = fmaf(av, wB.x, acc[r][4]);
                    acc[r][5] = fmaf(av, wB.y, acc[r][5]);
                    acc[r][6] = fmaf(av, wB.z, acc[r][6]);
                    acc[r][7] = fmaf(av, wB.w, acc[r][7]);
                }
            }
        }
        __syncthreads();
    }

    // epilogue: fold b_l into BN shift, then relu
    float sc[8], sh[8];
#pragma unroll
    for (int q = 0; q < 8; ++q) {
        int c = (q < 4) ? (c0 + q) : (c1 + q - 4);
        float s = bng[c] * rsqrtf(bnv[c] + 1e-5f);
        sc[q] = s;
        sh[q] = (bl[c] - bnm[c]) * s + bnb[c];
    }
#pragma unroll
    for (int r = 0; r < 8; ++r) {
        int row = row0 + r;
        if (row < N_NODES) {
            float4 o0, o1;
            o0.x = fmaxf(fmaf(acc[r][0], sc[0], sh[0]), 0.f);
            o0.y = fmaxf(fmaf(acc[r][1], sc[1], sh[1]), 0.f);
            o0.z = fmaxf(fmaf(acc[r][2], sc[2], sh[2]), 0.f);
            o0.w = fmaxf(fmaf(acc[r][3], sc[3], sh[3]), 0.f);
            o1.x = fmaxf(fmaf(acc[r][4], sc[4], sh[4]), 0.f);
            o1.y = fmaxf(fmaf(acc[r][5], sc[5], sh[5]), 0.f);
            o1.z = fmaxf(fmaf(acc[r][6], sc[6], sh[6]), 0.f);
            o1.w = fmaxf(fmaf(acc[r][7], sc[7], sh[7]), 0.f);
            *(float4*)(out + (size_t)row * 128 + c0) = o0;
            *(float4*)(out + (size_t)row * 128 + c1) = o1;
        }
    }
}

// ---------------------------------------------------------------- layer 3
// transform-then-aggregate: t4 = h2 @ [w3_l | w3_r]  -> [N,4]
__global__ void k_lin3(const float* __restrict__ h, const float* __restrict__ w3l,
                       const float* __restrict__ w3r, float* __restrict__ t4) {
    const int lane = threadIdx.x & 63;
    const int node = blockIdx.x * (blockDim.x >> 6) + (threadIdx.x >> 6);
    if (node >= N_NODES) return;
    float h0 = h[(size_t)node * 128 + lane];
    float h1 = h[(size_t)node * 128 + 64 + lane];
    float2 wl0 = *(const float2*)(w3l + lane * 2);
    float2 wl1 = *(const float2*)(w3l + (64 + lane) * 2);
    float2 wr0 = *(const float2*)(w3r + lane * 2);
    float2 wr1 = *(const float2*)(w3r + (64 + lane) * 2);
    float p0 = h0 * wl0.x + h1 * wl1.x;
    float p1 = h0 * wl0.y + h1 * wl1.y;
    float p2 = h0 * wr0.x + h1 * wr1.x;
    float p3 = h0 * wr0.y + h1 * wr1.y;
#pragma unroll
    for (int m = 1; m < 64; m <<= 1) {
        p0 += __shfl_xor(p0, m, 64);
        p1 += __shfl_xor(p1, m, 64);
        p2 += __shfl_xor(p2, m, 64);
        p3 += __shfl_xor(p3, m, 64);
    }
    if (lane == 0) {
        float4 o; o.x = p0; o.y = p1; o.z = p2; o.w = p3;
        *(float4*)(t4 + (size_t)node * 4) = o;
    }
}

// out[i] = (sum_e ew*t[src])/deg + b3 + r[i]   (t = t4[:,0:2], r = t4[:,2:4])
__global__ void k_out(const float* __restrict__ t4, const int* __restrict__ rowptr,
                      const int* __restrict__ col, const float* __restrict__ wgt,
                      const float* __restrict__ b3, float* __restrict__ out) {
    const int lane = threadIdx.x & 63;
    const int node = blockIdx.x * (blockDim.x >> 6) + (threadIdx.x >> 6);
    if (node >= N_NODES) return;
    const int s = rowptr[node], e = rowptr[node + 1];
    float a0 = 0.f, a1 = 0.f;
    for (int j = s + lane; j < e; j += 64) {
        int sr = col[j]; float w = wgt[j];
        float2 t = *(const float2*)(t4 + (size_t)sr * 4);
        a0 += w * t.x; a1 += w * t.y;
    }
#pragma unroll
    for (int m = 1; m < 64; m <<= 1) {
        a0 += __shfl_xor(a0, m, 64);
        a1 += __shfl_xor(a1, m, 64);
    }
    if (lane == 0) {
        float inv = 1.f / fmaxf((float)(e - s), 1.f);
        float2 o;
        o.x = a0 * inv + b3[0] + t4[(size_t)node * 4 + 2];
        o.y = a1 * inv + b3[1] + t4[(size_t)node * 4 + 3];
        *(float2*)(out + (size_t)node * 2) = o;
    }
}

// ---------------------------------------------------------------- launch
extern "C" void kernel_launch(void* const* d_in, const int* in_sizes, int n_in,
                              void* d_out, int out_size, void* d_ws, size_t ws_size,
                              hipStream_t stream) {
    const float* x    = (const float*)d_in[0];
    const float* ea   = (const float*)d_in[1];
    const int*   ei   = (const int*)d_in[2];
    const float* ew1w = (const float*)d_in[3];
    const float* ew1b = (const float*)d_in[4];
    const float* ew2w = (const float*)d_in[5];
    const float* ew2b = (const float*)d_in[6];
    const float* w1l  = (const float*)d_in[7];
    const float* b1l  = (const float*)d_in[8];
    const float* w1r  = (const float*)d_in[9];
    const float* w2l  = (const float*)d_in[10];
    const float* b2l  = (const float*)d_in[11];
    const float* w2r  = (const float*)d_in[12];
    const float* w3l  = (const float*)d_in[13];
    const float* b3l  = (const float*)d_in[14];
    const float* w3r  = (const float*)d_in[15];
    const float* bn1g = (const float*)d_in[16];
    const float* bn1b = (const float*)d_in[17];
    const float* bn1m = (const float*)d_in[18];
    const float* bn1v = (const float*)d_in[19];
    const float* bn2g = (const float*)d_in[20];
    const float* bn2b = (const float*)d_in[21];
    const float* bn2m = (const float*)d_in[22];
    const float* bn2v = (const float*)d_in[23];

    const int* src = ei;
    const int* dst = ei + N_EDGES;
    float* out = (float*)d_out;

    // workspace carve (total ~177 MB)
    size_t off = 0;
    auto carve = [&](size_t bytes) -> void* {
        void* p = (char*)d_ws + off;
        off += (bytes + 255) & ~(size_t)255;
        return p;
    };
    float* ew     = (float*)carve((size_t)N_EDGES * 4);
    int*   col    = (int*)carve((size_t)N_EDGES * 4);
    float* wgt    = (float*)carve((size_t)N_EDGES * 4);
    int*   rowptr = (int*)carve((size_t)(N_NODES + 1) * 4);
    int*   deg    = (int*)carve((size_t)N_NODES * 4);
    int*   cursor = (int*)carve((size_t)N_NODES * 4);
    int*   bsum   = (int*)carve(128 * 4);
    int*   boff   = (int*)carve(128 * 4);
    int*   incl   = (int*)carve((size_t)N_NODES * 4);
    float* agg    = (float*)carve((size_t)N_NODES * 128 * 4);
    float* hA     = (float*)carve((size_t)N_NODES * 128 * 4);
    float* hB     = (float*)carve((size_t)N_NODES * 128 * 4);
    float* t4     = (float*)carve((size_t)N_NODES * 4 * 4);
    (void)ws_size; (void)n_in; (void)in_sizes; (void)out_size;

    hipMemsetAsync(deg, 0, (size_t)N_NODES * 4, stream);
    hipMemsetAsync(cursor, 0, (size_t)N_NODES * 4, stream);

    const int EB = (N_EDGES + 255) / 256;       // 6250
    const int NB_SCAN = (N_NODES + 1023) / 1024; // 98
    const int NWB = (N_NODES + 3) / 4;          // 25000 (4 waves/block)
    const int GB = (N_NODES + 127) / 128;       // 782

    k_deg<<<EB, 256, 0, stream>>>(dst, deg);
    k_edge_mlp<<<2048, 256, 0, stream>>>(ea, ew1w, ew1b, ew2w, ew2b, ew);
    k_scan1<<<NB_SCAN, 1024, 0, stream>>>(deg, incl, bsum);
    k_scan2<<<1, 128, 0, stream>>>(bsum, boff, NB_SCAN);
    k_scan3<<<(N_NODES + 255) / 256, 256, 0, stream>>>(incl, boff, rowptr);
    k_fill<<<EB, 256, 0, stream>>>(src, dst, ew, rowptr, cursor, col, wgt);

    // layer 1
    k_agg<<<NWB, 256, 0, stream>>>(x, rowptr, col, wgt, agg);
    k_gemm_fused<<<GB, 256, 0, stream>>>(agg, x, w1l, w1r, b1l,
                                         bn1g, bn1b, bn1m, bn1v, hA);
    // layer 2
    k_agg<<<NWB, 256, 0, stream>>>(hA, rowptr, col, wgt, agg);
    k_gemm_fused<<<GB, 256, 0, stream>>>(agg, hA, w2l, w2r, b2l,
                                         bn2g, bn2b, bn2m, bn2v, hB);
    // layer 3 (transform-then-aggregate: only 2 floats/edge)
    k_lin3<<<NWB, 256, 0, stream>>>(hB, w3l, w3r, t4);
    k_out<<<NWB, 256, 0, stream>>>(t4, rowptr, col, wgt, b3l, out);
}

// Round 2
// 934.331 us; speedup vs baseline: 1.0522x; 1.0522x over previous
//
#include <hip/hip_runtime.h>
#include <math.h>

#define N_NODES 100000
#define N_EDGES 1600000
#define F_INF   128
#define HIDF    128

// ---------------------------------------------------------------- edge MLP
// 16 lanes per edge, 4 edges per wave. Each lane owns 8 hidden units; all its
// weights (8x8 w1 + 8 b1 + 8 w2) live in VGPRs, loaded once per thread.
// Per edge: ~20 VALU wave-instrs + 4-step shuffle reduce over 16 lanes.
__global__ __launch_bounds__(256) void k_edge_mlp(
        const float* __restrict__ ea,
        const float* __restrict__ w1, const float* __restrict__ b1,
        const float* __restrict__ w2, const float* __restrict__ b2,
        float* __restrict__ ew) {
    const int lane = threadIdx.x & 63;
    const int sub  = lane & 15;     // lane within edge-group
    const int grp  = lane >> 4;     // which of 4 edges this wave handles
    const int wid  = blockIdx.x * (blockDim.x >> 6) + (threadIdx.x >> 6);
    const int nw   = gridDim.x * (blockDim.x >> 6);

    // hidden units h = sub*8 + i for this lane
    float w1r[8][8], b1r[8], w2r[8];
#pragma unroll
    for (int i = 0; i < 8; ++i) {
        const int h = sub * 8 + i;
#pragma unroll
        for (int k = 0; k < 8; ++k) w1r[k][i] = w1[k * 128 + h];
        b1r[i] = b1[h];
        w2r[i] = w2[h];
    }
    const float bias2 = b2[0];

    // N_EDGES % 4 == 0 and stride is a multiple of 4, so e = e0+grp is in range.
    for (int e0 = wid * 4; e0 < N_EDGES; e0 += nw * 4) {
        const int e = e0 + grp;
        const float4 a0 = *(const float4*)(ea + (size_t)e * 8);
        const float4 a1 = *(const float4*)(ea + (size_t)e * 8 + 4);
        const float a[8] = {a0.x, a0.y, a0.z, a0.w, a1.x, a1.y, a1.z, a1.w};
        float p = 0.f;
#pragma unroll
        for (int i = 0; i < 8; ++i) {
            float h = b1r[i];
#pragma unroll
            for (int k = 0; k < 8; ++k) h = fmaf(a[k], w1r[k][i], h);
            p = fmaf(fmaxf(h, 0.f), w2r[i], p);
        }
        // reduce across the 16 lanes of this edge-group
        p += __shfl_xor(p, 1, 64);
        p += __shfl_xor(p, 2, 64);
        p += __shfl_xor(p, 4, 64);
        p += __shfl_xor(p, 8, 64);
        if (sub == 0) {
            const float z = p + bias2;
            ew[e] = 1.f / (1.f + __expf(-z));  // lanes 0,16,32,48 -> 16B segment
        }
    }
}

// ---------------------------------------------------------------- CSR build
__global__ void k_deg(const int* __restrict__ dst, int* __restrict__ deg) {
    int e = blockIdx.x * 256 + threadIdx.x;
    if (e < N_EDGES) atomicAdd(&deg[dst[e]], 1);
}

__global__ void k_scan1(const int* __restrict__ deg, int* __restrict__ incl,
                        int* __restrict__ bsum) {
    __shared__ int sm[1024];
    const int tid = threadIdx.x;
    const int gi  = blockIdx.x * 1024 + tid;
    int v = (gi < N_NODES) ? deg[gi] : 0;
    sm[tid] = v;
    __syncthreads();
    for (int off = 1; off < 1024; off <<= 1) {
        int t = (tid >= off) ? sm[tid - off] : 0;
        __syncthreads();
        sm[tid] += t;
        __syncthreads();
    }
    if (gi < N_NODES) incl[gi] = sm[tid];
    if (tid == 1023) bsum[blockIdx.x] = sm[1023];
}

__global__ void k_scan2(const int* __restrict__ bsum, int* __restrict__ boff, int nb) {
    __shared__ int sm[128];
    const int tid = threadIdx.x;  // 128 threads
    int v = (tid < nb) ? bsum[tid] : 0;
    sm[tid] = v;
    __syncthreads();
    for (int off = 1; off < 128; off <<= 1) {
        int t = (tid >= off) ? sm[tid - off] : 0;
        __syncthreads();
        sm[tid] += t;
        __syncthreads();
    }
    boff[tid] = sm[tid] - v;  // exclusive
}

__global__ void k_scan3(const int* __restrict__ incl, const int* __restrict__ boff,
                        int* __restrict__ rowptr) {
    int i = blockIdx.x * 256 + threadIdx.x;
    if (i < N_NODES) rowptr[i + 1] = boff[i >> 10] + incl[i];
    if (i == 0) rowptr[0] = 0;
}

__global__ void k_fill(const int* __restrict__ src, const int* __restrict__ dst,
                       const float* __restrict__ ew, const int* __restrict__ rowptr,
                       int* __restrict__ cursor, int* __restrict__ col,
                       float* __restrict__ wgt) {
    int e = blockIdx.x * 256 + threadIdx.x;
    if (e < N_EDGES) {
        int d   = dst[e];
        int pos = rowptr[d] + atomicAdd(&cursor[d], 1);
        col[pos] = src[e];
        wgt[pos] = ew[e];
    }
}

// ---------------------------------------------------------------- aggregation
// wave per node; lane covers feature cols {lane*2, lane*2+1}; each edge is one
// wave-coalesced 512B row gather. 4-wide unroll for memory-level parallelism.
__global__ void k_agg(const float* __restrict__ xin, const int* __restrict__ rowptr,
                      const int* __restrict__ col, const float* __restrict__ wgt,
                      float* __restrict__ aggout) {
    const int lane = threadIdx.x & 63;
    const int node = blockIdx.x * (blockDim.x >> 6) + (threadIdx.x >> 6);
    if (node >= N_NODES) return;
    const int s = rowptr[node], e = rowptr[node + 1];
    float ax = 0.f, ay = 0.f;
    int j = s;
    for (; j + 4 <= e; j += 4) {
        int   s0 = col[j],   s1 = col[j + 1],  s2 = col[j + 2],  s3 = col[j + 3];
        float w0 = wgt[j],   w1 = wgt[j + 1],  w2 = wgt[j + 2],  w3 = wgt[j + 3];
        float2 v0 = *(const float2*)(xin + (size_t)s0 * 128 + lane * 2);
        float2 v1 = *(const float2*)(xin + (size_t)s1 * 128 + lane * 2);
        float2 v2 = *(const float2*)(xin + (size_t)s2 * 128 + lane * 2);
        float2 v3 = *(const float2*)(xin + (size_t)s3 * 128 + lane * 2);
        ax += w0 * v0.x + w1 * v1.x + w2 * v2.x + w3 * v3.x;
        ay += w0 * v0.y + w1 * v1.y + w2 * v2.y + w3 * v3.y;
    }
    for (; j < e; ++j) {
        int s0 = col[j]; float w0 = wgt[j];
        float2 v0 = *(const float2*)(xin + (size_t)s0 * 128 + lane * 2);
        ax += w0 * v0.x; ay += w0 * v0.y;
    }
    const float inv = 1.f / fmaxf((float)(e - s), 1.f);
    float2 r; r.x = ax * inv; r.y = ay * inv;
    *(float2*)(aggout + (size_t)node * 128 + lane * 2) = r;
}

// ---------------------------------------------------------------- fused GEMM
// h = relu(bn(agg@Wl + b_l + x@Wr)) as one K=256 GEMM.
// 128x128 block tile, 256 threads, 8 rows x 8 cols per thread (cols split c0 /
// c0+64 so LDS b128 reads alias banks only 2-way = free). W k-tile in LDS (32KB),
// A straight from global (16B loads broadcast to 16 lanes).
__global__ __launch_bounds__(256) void k_gemm_fused(
    const float* __restrict__ Aagg, const float* __restrict__ Ax,
    const float* __restrict__ Wl, const float* __restrict__ Wr,
    const float* __restrict__ bl,
    const float* __restrict__ bng, const float* __restrict__ bnb,
    const float* __restrict__ bnm, const float* __restrict__ bnv,
    float* __restrict__ out) {
    __shared__ float Ws[64 * 128];
    const int tid  = threadIdx.x;
    const int cg   = tid & 15;
    const int rg   = tid >> 4;
    const int row0 = blockIdx.x * 128 + rg * 8;
    const int c0   = cg * 4, c1 = 64 + cg * 4;

    int rows[8];
#pragma unroll
    for (int r = 0; r < 8; ++r) rows[r] = min(row0 + r, N_NODES - 1);

    float acc[8][8];
#pragma unroll
    for (int r = 0; r < 8; ++r)
#pragma unroll
        for (int q = 0; q < 8; ++q) acc[r][q] = 0.f;

    for (int kt = 0; kt < 4; ++kt) {
        const float* Wsrc  = (kt < 2) ? Wl : Wr;
        const float* Asrc  = (kt < 2) ? Aagg : Ax;
        const int    kbase = (kt & 1) * 64;
        // stage 64x128 W tile (contiguous slab)
#pragma unroll
        for (int i = 0; i < 8; ++i) {
            int fi = tid * 4 + i * 1024;
            *(float4*)(Ws + fi) = *(const float4*)(Wsrc + (size_t)kbase * 128 + fi);
        }
        __syncthreads();
#pragma unroll 2
        for (int k4 = 0; k4 < 64; k4 += 4) {
            float4 a[8];
#pragma unroll
            for (int r = 0; r < 8; ++r)
                a[r] = *(const float4*)(Asrc + (size_t)rows[r] * 128 + kbase + k4);
#pragma unroll
            for (int kk = 0; kk < 4; ++kk) {
                const float4 wA = *(const float4*)(Ws + (k4 + kk) * 128 + c0);
                const float4 wB = *(const float4*)(Ws + (k4 + kk) * 128 + c1);
#pragma unroll
                for (int r = 0; r < 8; ++r) {
                    float av = (kk == 0) ? a[r].x : (kk == 1) ? a[r].y
                              : (kk == 2) ? a[r].z : a[r].w;
                    acc[r][0] = fmaf(av, wA.x, acc[r][0]);
                    acc[r][1] = fmaf(av, wA.y, acc[r][1]);
                    acc[r][2] = fmaf(av, wA.z, acc[r][2]);
                    acc[r][3] = fmaf(av, wA.w, acc[r][3]);
                    acc[r][4] = fmaf(av, wB.x, acc[r][4]);
                    acc[r][5] = fmaf(av, wB.y, acc[r][5]);
                    acc[r][6] = fmaf(av, wB.z, acc[r][6]);
                    acc[r][7] = fmaf(av, wB.w, acc[r][7]);
                }
            }
        }
        __syncthreads();
    }

    // epilogue: fold b_l into BN shift, then relu
    float sc[8], sh[8];
#pragma unroll
    for (int q = 0; q < 8; ++q) {
        int c = (q < 4) ? (c0 + q) : (c1 + q - 4);
        float s = bng[c] * rsqrtf(bnv[c] + 1e-5f);
        sc[q] = s;
        sh[q] = (bl[c] - bnm[c]) * s + bnb[c];
    }
#pragma unroll
    for (int r = 0; r < 8; ++r) {
        int row = row0 + r;
        if (row < N_NODES) {
            float4 o0, o1;
            o0.x = fmaxf(fmaf(acc[r][0], sc[0], sh[0]), 0.f);
            o0.y = fmaxf(fmaf(acc[r][1], sc[1], sh[1]), 0.f);
            o0.z = fmaxf(fmaf(acc[r][2], sc[2], sh[2]), 0.f);
            o0.w = fmaxf(fmaf(acc[r][3], sc[3], sh[3]), 0.f);
            o1.x = fmaxf(fmaf(acc[r][4], sc[4], sh[4]), 0.f);
            o1.y = fmaxf(fmaf(acc[r][5], sc[5], sh[5]), 0.f);
            o1.z = fmaxf(fmaf(acc[r][6], sc[6], sh[6]), 0.f);
            o1.w = fmaxf(fmaf(acc[r][7], sc[7], sh[7]), 0.f);
            *(float4*)(out + (size_t)row * 128 + c0) = o0;
            *(float4*)(out + (size_t)row * 128 + c1) = o1;
        }
    }
}

// ---------------------------------------------------------------- layer 3
// transform-then-aggregate: t4 = h2 @ [w3_l | w3_r]  -> [N,4]
__global__ void k_lin3(const float* __restrict__ h, const float* __restrict__ w3l,
                       const float* __restrict__ w3r, float* __restrict__ t4) {
    const int lane = threadIdx.x & 63;
    const int node = blockIdx.x * (blockDim.x >> 6) + (threadIdx.x >> 6);
    if (node >= N_NODES) return;
    float h0 = h[(size_t)node * 128 + lane];
    float h1 = h[(size_t)node * 128 + 64 + lane];
    float2 wl0 = *(const float2*)(w3l + lane * 2);
    float2 wl1 = *(const float2*)(w3l + (64 + lane) * 2);
    float2 wr0 = *(const float2*)(w3r + lane * 2);
    float2 wr1 = *(const float2*)(w3r + (64 + lane) * 2);
    float p0 = h0 * wl0.x + h1 * wl1.x;
    float p1 = h0 * wl0.y + h1 * wl1.y;
    float p2 = h0 * wr0.x + h1 * wr1.x;
    float p3 = h0 * wr0.y + h1 * wr1.y;
#pragma unroll
    for (int m = 1; m < 64; m <<= 1) {
        p0 += __shfl_xor(p0, m, 64);
        p1 += __shfl_xor(p1, m, 64);
        p2 += __shfl_xor(p2, m, 64);
        p3 += __shfl_xor(p3, m, 64);
    }
    if (lane == 0) {
        float4 o; o.x = p0; o.y = p1; o.z = p2; o.w = p3;
        *(float4*)(t4 + (size_t)node * 4) = o;
    }
}

// out[i] = (sum_e ew*t[src])/deg + b3 + r[i]   (t = t4[:,0:2], r = t4[:,2:4])
__global__ void k_out(const float* __restrict__ t4, const int* __restrict__ rowptr,
                      const int* __restrict__ col, const float* __restrict__ wgt,
                      const float* __restrict__ b3, float* __restrict__ out) {
    const int lane = threadIdx.x & 63;
    const int node = blockIdx.x * (blockDim.x >> 6) + (threadIdx.x >> 6);
    if (node >= N_NODES) return;
    const int s = rowptr[node], e = rowptr[node + 1];
    float a0 = 0.f, a1 = 0.f;
    for (int j = s + lane; j < e; j += 64) {
        int sr = col[j]; float w = wgt[j];
        float2 t = *(const float2*)(t4 + (size_t)sr * 4);
        a0 += w * t.x; a1 += w * t.y;
    }
#pragma unroll
    for (int m = 1; m < 64; m <<= 1) {
        a0 += __shfl_xor(a0, m, 64);
        a1 += __shfl_xor(a1, m, 64);
    }
    if (lane == 0) {
        float inv = 1.f / fmaxf((float)(e - s), 1.f);
        float2 o;
        o.x = a0 * inv + b3[0] + t4[(size_t)node * 4 + 2];
        o.y = a1 * inv + b3[1] + t4[(size_t)node * 4 + 3];
        *(float2*)(out + (size_t)node * 2) = o;
    }
}

// ---------------------------------------------------------------- launch
extern "C" void kernel_launch(void* const* d_in, const int* in_sizes, int n_in,
                              void* d_out, int out_size, void* d_ws, size_t ws_size,
                              hipStream_t stream) {
    const float* x    = (const float*)d_in[0];
    const float* ea   = (const float*)d_in[1];
    const int*   ei   = (const int*)d_in[2];
    const float* ew1w = (const float*)d_in[3];
    const float* ew1b = (const float*)d_in[4];
    const float* ew2w = (const float*)d_in[5];
    const float* ew2b = (const float*)d_in[6];
    const float* w1l  = (const float*)d_in[7];
    const float* b1l  = (const float*)d_in[8];
    const float* w1r  = (const float*)d_in[9];
    const float* w2l  = (const float*)d_in[10];
    const float* b2l  = (const float*)d_in[11];
    const float* w2r  = (const float*)d_in[12];
    const float* w3l  = (const float*)d_in[13];
    const float* b3l  = (const float*)d_in[14];
    const float* w3r  = (const float*)d_in[15];
    const float* bn1g = (const float*)d_in[16];
    const float* bn1b = (const float*)d_in[17];
    const float* bn1m = (const float*)d_in[18];
    const float* bn1v = (const float*)d_in[19];
    const float* bn2g = (const float*)d_in[20];
    const float* bn2b = (const float*)d_in[21];
    const float* bn2m = (const float*)d_in[22];
    const float* bn2v = (const float*)d_in[23];

    const int* src = ei;
    const int* dst = ei + N_EDGES;
    float* out = (float*)d_out;

    // workspace carve (total ~177 MB)
    size_t off = 0;
    auto carve = [&](size_t bytes) -> void* {
        void* p = (char*)d_ws + off;
        off += (bytes + 255) & ~(size_t)255;
        return p;
    };
    float* ew     = (float*)carve((size_t)N_EDGES * 4);
    int*   col    = (int*)carve((size_t)N_EDGES * 4);
    float* wgt    = (float*)carve((size_t)N_EDGES * 4);
    int*   rowptr = (int*)carve((size_t)(N_NODES + 1) * 4);
    int*   deg    = (int*)carve((size_t)N_NODES * 4);
    int*   cursor = (int*)carve((size_t)N_NODES * 4);
    int*   bsum   = (int*)carve(128 * 4);
    int*   boff   = (int*)carve(128 * 4);
    int*   incl   = (int*)carve((size_t)N_NODES * 4);
    float* agg    = (float*)carve((size_t)N_NODES * 128 * 4);
    float* hA     = (float*)carve((size_t)N_NODES * 128 * 4);
    float* hB     = (float*)carve((size_t)N_NODES * 128 * 4);
    float* t4     = (float*)carve((size_t)N_NODES * 4 * 4);
    (void)ws_size; (void)n_in; (void)in_sizes; (void)out_size;

    hipMemsetAsync(deg, 0, (size_t)N_NODES * 4, stream);
    hipMemsetAsync(cursor, 0, (size_t)N_NODES * 4, stream);

    const int EB = (N_EDGES + 255) / 256;       // 6250
    const int NB_SCAN = (N_NODES + 1023) / 1024; // 98
    const int NWB = (N_NODES + 3) / 4;          // 25000 (4 waves/block)
    const int GB = (N_NODES + 127) / 128;       // 782

    k_deg<<<EB, 256, 0, stream>>>(dst, deg);
    k_edge_mlp<<<1024, 256, 0, stream>>>(ea, ew1w, ew1b, ew2w, ew2b, ew);
    k_scan1<<<NB_SCAN, 1024, 0, stream>>>(deg, incl, bsum);
    k_scan2<<<1, 128, 0, stream>>>(bsum, boff, NB_SCAN);
    k_scan3<<<(N_NODES + 255) / 256, 256, 0, stream>>>(incl, boff, rowptr);
    k_fill<<<EB, 256, 0, stream>>>(src, dst, ew, rowptr, cursor, col, wgt);

    // layer 1
    k_agg<<<NWB, 256, 0, stream>>>(x, rowptr, col, wgt, agg);
    k_gemm_fused<<<GB, 256, 0, stream>>>(agg, x, w1l, w1r, b1l,
                                         bn1g, bn1b, bn1m, bn1v, hA);
    // layer 2
    k_agg<<<NWB, 256, 0, stream>>>(hA, rowptr, col, wgt, agg);
    k_gemm_fused<<<GB, 256, 0, stream>>>(agg, hA, w2l, w2r, b2l,
                                         bn2g, bn2b, bn2m, bn2v, hB);
    // layer 3 (transform-then-aggregate: only 2 floats/edge)
    k_lin3<<<NWB, 256, 0, stream>>>(hB, w3l, w3r, t4);
    k_out<<<NWB, 256, 0, stream>>>(t4, rowptr, col, wgt, b3l, out);
}

// Round 3
// 796.132 us; speedup vs baseline: 1.2348x; 1.1736x over previous
//
#include <hip/hip_runtime.h>
#include <math.h>

#define N_NODES 100000
#define N_EDGES 1600000
#define F_INF   128
#define HIDF    128

typedef __attribute__((ext_vector_type(8)))  short short8;
typedef __attribute__((ext_vector_type(16))) float floatx16;

// ---------------------------------------------------------------- edge MLP
// 16 lanes per edge, 4 edges per wave. Each lane owns 8 hidden units; all its
// weights (8x8 w1 + 8 b1 + 8 w2) live in VGPRs, loaded once per thread.
__global__ __launch_bounds__(256) void k_edge_mlp(
        const float* __restrict__ ea,
        const float* __restrict__ w1, const float* __restrict__ b1,
        const float* __restrict__ w2, const float* __restrict__ b2,
        float* __restrict__ ew) {
    const int lane = threadIdx.x & 63;
    const int sub  = lane & 15;     // lane within edge-group
    const int grp  = lane >> 4;     // which of 4 edges this wave handles
    const int wid  = blockIdx.x * (blockDim.x >> 6) + (threadIdx.x >> 6);
    const int nw   = gridDim.x * (blockDim.x >> 6);

    float w1r[8][8], b1r[8], w2r[8];
#pragma unroll
    for (int i = 0; i < 8; ++i) {
        const int h = sub * 8 + i;
#pragma unroll
        for (int k = 0; k < 8; ++k) w1r[k][i] = w1[k * 128 + h];
        b1r[i] = b1[h];
        w2r[i] = w2[h];
    }
    const float bias2 = b2[0];

    for (int e0 = wid * 4; e0 < N_EDGES; e0 += nw * 4) {
        const int e = e0 + grp;
        const float4 a0 = *(const float4*)(ea + (size_t)e * 8);
        const float4 a1 = *(const float4*)(ea + (size_t)e * 8 + 4);
        const float a[8] = {a0.x, a0.y, a0.z, a0.w, a1.x, a1.y, a1.z, a1.w};
        float p = 0.f;
#pragma unroll
        for (int i = 0; i < 8; ++i) {
            float h = b1r[i];
#pragma unroll
            for (int k = 0; k < 8; ++k) h = fmaf(a[k], w1r[k][i], h);
            p = fmaf(fmaxf(h, 0.f), w2r[i], p);
        }
        p += __shfl_xor(p, 1, 64);
        p += __shfl_xor(p, 2, 64);
        p += __shfl_xor(p, 4, 64);
        p += __shfl_xor(p, 8, 64);
        if (sub == 0) {
            const float z = p + bias2;
            ew[e] = 1.f / (1.f + __expf(-z));
        }
    }
}

// ---------------------------------------------------------------- CSR build
__global__ void k_deg(const int* __restrict__ dst, int* __restrict__ deg) {
    int e = blockIdx.x * 256 + threadIdx.x;
    if (e < N_EDGES) atomicAdd(&deg[dst[e]], 1);
}

__global__ void k_scan1(const int* __restrict__ deg, int* __restrict__ incl,
                        int* __restrict__ bsum) {
    __shared__ int sm[1024];
    const int tid = threadIdx.x;
    const int gi  = blockIdx.x * 1024 + tid;
    int v = (gi < N_NODES) ? deg[gi] : 0;
    sm[tid] = v;
    __syncthreads();
    for (int off = 1; off < 1024; off <<= 1) {
        int t = (tid >= off) ? sm[tid - off] : 0;
        __syncthreads();
        sm[tid] += t;
        __syncthreads();
    }
    if (gi < N_NODES) incl[gi] = sm[tid];
    if (tid == 1023) bsum[blockIdx.x] = sm[1023];
}

__global__ void k_scan2(const int* __restrict__ bsum, int* __restrict__ boff, int nb) {
    __shared__ int sm[128];
    const int tid = threadIdx.x;
    int v = (tid < nb) ? bsum[tid] : 0;
    sm[tid] = v;
    __syncthreads();
    for (int off = 1; off < 128; off <<= 1) {
        int t = (tid >= off) ? sm[tid - off] : 0;
        __syncthreads();
        sm[tid] += t;
        __syncthreads();
    }
    boff[tid] = sm[tid] - v;
}

__global__ void k_scan3(const int* __restrict__ incl, const int* __restrict__ boff,
                        int* __restrict__ rowptr) {
    int i = blockIdx.x * 256 + threadIdx.x;
    if (i < N_NODES) rowptr[i + 1] = boff[i >> 10] + incl[i];
    if (i == 0) rowptr[0] = 0;
}

__global__ void k_fill(const int* __restrict__ src, const int* __restrict__ dst,
                       const float* __restrict__ ew, const int* __restrict__ rowptr,
                       int* __restrict__ cursor, int* __restrict__ col,
                       float* __restrict__ wgt) {
    int e = blockIdx.x * 256 + threadIdx.x;
    if (e < N_EDGES) {
        int d   = dst[e];
        int pos = rowptr[d] + atomicAdd(&cursor[d], 1);
        col[pos] = src[e];
        wgt[pos] = ew[e];
    }
}

// ---------------------------------------------------------------- aggregation
__global__ void k_agg(const float* __restrict__ xin, const int* __restrict__ rowptr,
                      const int* __restrict__ col, const float* __restrict__ wgt,
                      float* __restrict__ aggout) {
    const int lane = threadIdx.x & 63;
    const int node = blockIdx.x * (blockDim.x >> 6) + (threadIdx.x >> 6);
    if (node >= N_NODES) return;
    const int s = rowptr[node], e = rowptr[node + 1];
    float ax = 0.f, ay = 0.f;
    int j = s;
    for (; j + 4 <= e; j += 4) {
        int   s0 = col[j],   s1 = col[j + 1],  s2 = col[j + 2],  s3 = col[j + 3];
        float w0 = wgt[j],   w1 = wgt[j + 1],  w2 = wgt[j + 2],  w3 = wgt[j + 3];
        float2 v0 = *(const float2*)(xin + (size_t)s0 * 128 + lane * 2);
        float2 v1 = *(const float2*)(xin + (size_t)s1 * 128 + lane * 2);
        float2 v2 = *(const float2*)(xin + (size_t)s2 * 128 + lane * 2);
        float2 v3 = *(const float2*)(xin + (size_t)s3 * 128 + lane * 2);
        ax += w0 * v0.x + w1 * v1.x + w2 * v2.x + w3 * v3.x;
        ay += w0 * v0.y + w1 * v1.y + w2 * v2.y + w3 * v3.y;
    }
    for (; j < e; ++j) {
        int s0 = col[j]; float w0 = wgt[j];
        float2 v0 = *(const float2*)(xin + (size_t)s0 * 128 + lane * 2);
        ax += w0 * v0.x; ay += w0 * v0.y;
    }
    const float inv = 1.f / fmaxf((float)(e - s), 1.f);
    float2 r; r.x = ax * inv; r.y = ay * inv;
    *(float2*)(aggout + (size_t)node * 128 + lane * 2) = r;
}

// ---------------------------------------------------------------- W packing
// Pack [Wl;Wr] (fp32, K=256 x N=128 row-major) into MFMA B-fragment order for
// v_mfma_f32_32x32x16_bf16, split into hi/lo bf16 (RNE + residual).
// Storage: off = ((kb*4 + cb)*64 + lane)*8 + j, where
//   k = kb*16 + (lane>>5)*8 + j, n = cb*32 + (lane&31).
__global__ void k_wpack(const float* __restrict__ Wl, const float* __restrict__ Wr,
                        short* __restrict__ Whi, short* __restrict__ Wlo) {
    int idx = blockIdx.x * 256 + threadIdx.x;   // 32768 total
    int j  = idx & 7;
    int L  = (idx >> 3) & 63;
    int cb = (idx >> 9) & 3;
    int kb = (idx >> 11);
    int k  = kb * 16 + (L >> 5) * 8 + j;
    int n  = cb * 32 + (L & 31);
    float a = (k < 128) ? Wl[k * 128 + n] : Wr[(k - 128) * 128 + n];
    unsigned u  = __float_as_uint(a);
    unsigned hb = (u + 0x7FFFu + ((u >> 16) & 1u)) >> 16;
    float    hf = __uint_as_float(hb << 16);
    float    r  = a - hf;
    unsigned v  = __float_as_uint(r);
    unsigned lb = (v + 0x7FFFu + ((v >> 16) & 1u)) >> 16;
    Whi[idx] = (short)hb;
    Wlo[idx] = (short)lb;
}

// ---------------------------------------------------------------- MFMA GEMM
// h = relu(bn(agg@Wl + b_l + x@Wr)), K=256, via v_mfma_f32_32x32x16_bf16 with
// split-bf16: C = Ah*Wh + Al*Wh + Ah*Wl (error ~2^-17 rel, ~fp32 quality).
// No LDS: A loaded fp32 from global in fragment layout (lane&31 = row,
// (lane>>5)*8 = k-offset), split on the fly; W pre-packed fragment-ready.
// Block = 4 waves; wave computes 32 rows x 128 cols (4 acc frags of 32x32).
__global__ __launch_bounds__(256) void k_gemm_mfma(
    const float* __restrict__ Aagg, const float* __restrict__ Ax,
    const short* __restrict__ Whi, const short* __restrict__ Wlo,
    const float* __restrict__ bl,
    const float* __restrict__ bng, const float* __restrict__ bnb,
    const float* __restrict__ bnm, const float* __restrict__ bnv,
    float* __restrict__ out) {
    const int tid  = threadIdx.x;
    const int lane = tid & 63;
    const int w    = tid >> 6;                    // wave 0..3
    const int row0 = blockIdx.x * 128 + w * 32;
    const int rrow = lane & 31;
    const int kq   = lane >> 5;                   // k-offset group (0/1)
    const int arow = min(row0 + rrow, N_NODES - 1);

    floatx16 acc[4];
#pragma unroll
    for (int cb = 0; cb < 4; ++cb)
#pragma unroll
        for (int r = 0; r < 16; ++r) acc[cb][r] = 0.f;

    const float* Abase0 = Aagg + (size_t)arow * 128 + kq * 8;
    const float* Abase1 = Ax   + (size_t)arow * 128 + kq * 8;

#pragma unroll 2
    for (int kb = 0; kb < 16; ++kb) {
        const float* ap = ((kb < 8) ? Abase0 : Abase1) + (kb & 7) * 16;
        const float4 a0 = *(const float4*)(ap);
        const float4 a1 = *(const float4*)(ap + 4);
        const float av[8] = {a0.x, a0.y, a0.z, a0.w, a1.x, a1.y, a1.z, a1.w};
        short8 Ah, Al;
#pragma unroll
        for (int j = 0; j < 8; ++j) {
            unsigned u  = __float_as_uint(av[j]);
            unsigned hb = (u + 0x7FFFu + ((u >> 16) & 1u)) >> 16;
            float    hf = __uint_as_float(hb << 16);
            float    r  = av[j] - hf;
            unsigned v  = __float_as_uint(r);
            unsigned lb = (v + 0x7FFFu + ((v >> 16) & 1u)) >> 16;
            Ah[j] = (short)hb;
            Al[j] = (short)lb;
        }
#pragma unroll
        for (int cb = 0; cb < 4; ++cb) {
            const size_t wo = ((size_t)(kb * 4 + cb) * 64 + lane) * 8;
            const short8 wh = *(const short8*)(Whi + wo);
            const short8 wl = *(const short8*)(Wlo + wo);
            acc[cb] = __builtin_amdgcn_mfma_f32_32x32x16_bf16(Ah, wh, acc[cb], 0, 0, 0);
            acc[cb] = __builtin_amdgcn_mfma_f32_32x32x16_bf16(Al, wh, acc[cb], 0, 0, 0);
            acc[cb] = __builtin_amdgcn_mfma_f32_32x32x16_bf16(Ah, wl, acc[cb], 0, 0, 0);
        }
    }

    // epilogue: BN(fold b_l) + ReLU; C/D layout col=lane&31,
    // row=(reg&3)+8*(reg>>2)+4*(lane>>5)
#pragma unroll
    for (int cb = 0; cb < 4; ++cb) {
        const int c = cb * 32 + (lane & 31);
        const float s = bng[c] * rsqrtf(bnv[c] + 1e-5f);
        const float t = (bl[c] - bnm[c]) * s + bnb[c];
#pragma unroll
        for (int r = 0; r < 16; ++r) {
            const int row = row0 + (r & 3) + 8 * (r >> 2) + 4 * kq;
            if (row < N_NODES)
                out[(size_t)row * 128 + c] = fmaxf(fmaf(acc[cb][r], s, t), 0.f);
        }
    }
}

// ---------------------------------------------------------------- layer 3
__global__ void k_lin3(const float* __restrict__ h, const float* __restrict__ w3l,
                       const float* __restrict__ w3r, float* __restrict__ t4) {
    const int lane = threadIdx.x & 63;
    const int node = blockIdx.x * (blockDim.x >> 6) + (threadIdx.x >> 6);
    if (node >= N_NODES) return;
    float h0 = h[(size_t)node * 128 + lane];
    float h1 = h[(size_t)node * 128 + 64 + lane];
    float2 wl0 = *(const float2*)(w3l + lane * 2);
    float2 wl1 = *(const float2*)(w3l + (64 + lane) * 2);
    float2 wr0 = *(const float2*)(w3r + lane * 2);
    float2 wr1 = *(const float2*)(w3r + (64 + lane) * 2);
    float p0 = h0 * wl0.x + h1 * wl1.x;
    float p1 = h0 * wl0.y + h1 * wl1.y;
    float p2 = h0 * wr0.x + h1 * wr1.x;
    float p3 = h0 * wr0.y + h1 * wr1.y;
#pragma unroll
    for (int m = 1; m < 64; m <<= 1) {
        p0 += __shfl_xor(p0, m, 64);
        p1 += __shfl_xor(p1, m, 64);
        p2 += __shfl_xor(p2, m, 64);
        p3 += __shfl_xor(p3, m, 64);
    }
    if (lane == 0) {
        float4 o; o.x = p0; o.y = p1; o.z = p2; o.w = p3;
        *(float4*)(t4 + (size_t)node * 4) = o;
    }
}

__global__ void k_out(const float* __restrict__ t4, const int* __restrict__ rowptr,
                      const int* __restrict__ col, const float* __restrict__ wgt,
                      const float* __restrict__ b3, float* __restrict__ out) {
    const int lane = threadIdx.x & 63;
    const int node = blockIdx.x * (blockDim.x >> 6) + (threadIdx.x >> 6);
    if (node >= N_NODES) return;
    const int s = rowptr[node], e = rowptr[node + 1];
    float a0 = 0.f, a1 = 0.f;
    for (int j = s + lane; j < e; j += 64) {
        int sr = col[j]; float w = wgt[j];
        float2 t = *(const float2*)(t4 + (size_t)sr * 4);
        a0 += w * t.x; a1 += w * t.y;
    }
#pragma unroll
    for (int m = 1; m < 64; m <<= 1) {
        a0 += __shfl_xor(a0, m, 64);
        a1 += __shfl_xor(a1, m, 64);
    }
    if (lane == 0) {
        float inv = 1.f / fmaxf((float)(e - s), 1.f);
        float2 o;
        o.x = a0 * inv + b3[0] + t4[(size_t)node * 4 + 2];
        o.y = a1 * inv + b3[1] + t4[(size_t)node * 4 + 3];
        *(float2*)(out + (size_t)node * 2) = o;
    }
}

// ---------------------------------------------------------------- launch
extern "C" void kernel_launch(void* const* d_in, const int* in_sizes, int n_in,
                              void* d_out, int out_size, void* d_ws, size_t ws_size,
                              hipStream_t stream) {
    const float* x    = (const float*)d_in[0];
    const float* ea   = (const float*)d_in[1];
    const int*   ei   = (const int*)d_in[2];
    const float* ew1w = (const float*)d_in[3];
    const float* ew1b = (const float*)d_in[4];
    const float* ew2w = (const float*)d_in[5];
    const float* ew2b = (const float*)d_in[6];
    const float* w1l  = (const float*)d_in[7];
    const float* b1l  = (const float*)d_in[8];
    const float* w1r  = (const float*)d_in[9];
    const float* w2l  = (const float*)d_in[10];
    const float* b2l  = (const float*)d_in[11];
    const float* w2r  = (const float*)d_in[12];
    const float* w3l  = (const float*)d_in[13];
    const float* b3l  = (const float*)d_in[14];
    const float* w3r  = (const float*)d_in[15];
    const float* bn1g = (const float*)d_in[16];
    const float* bn1b = (const float*)d_in[17];
    const float* bn1m = (const float*)d_in[18];
    const float* bn1v = (const float*)d_in[19];
    const float* bn2g = (const float*)d_in[20];
    const float* bn2b = (const float*)d_in[21];
    const float* bn2m = (const float*)d_in[22];
    const float* bn2v = (const float*)d_in[23];

    const int* src = ei;
    const int* dst = ei + N_EDGES;
    float* out = (float*)d_out;

    size_t off = 0;
    auto carve = [&](size_t bytes) -> void* {
        void* p = (char*)d_ws + off;
        off += (bytes + 255) & ~(size_t)255;
        return p;
    };
    float* ew     = (float*)carve((size_t)N_EDGES * 4);
    int*   col    = (int*)carve((size_t)N_EDGES * 4);
    float* wgt    = (float*)carve((size_t)N_EDGES * 4);
    int*   rowptr = (int*)carve((size_t)(N_NODES + 1) * 4);
    int*   deg    = (int*)carve((size_t)N_NODES * 4);
    int*   cursor = (int*)carve((size_t)N_NODES * 4);
    int*   bsum   = (int*)carve(128 * 4);
    int*   boff   = (int*)carve(128 * 4);
    int*   incl   = (int*)carve((size_t)N_NODES * 4);
    float* agg    = (float*)carve((size_t)N_NODES * 128 * 4);
    float* hA     = (float*)carve((size_t)N_NODES * 128 * 4);
    float* hB     = (float*)carve((size_t)N_NODES * 128 * 4);
    float* t4     = (float*)carve((size_t)N_NODES * 4 * 4);
    short* W1hi   = (short*)carve(32768 * 2);
    short* W1lo   = (short*)carve(32768 * 2);
    short* W2hi   = (short*)carve(32768 * 2);
    short* W2lo   = (short*)carve(32768 * 2);
    (void)ws_size; (void)n_in; (void)in_sizes; (void)out_size;

    hipMemsetAsync(deg, 0, (size_t)N_NODES * 4, stream);
    hipMemsetAsync(cursor, 0, (size_t)N_NODES * 4, stream);

    const int EB = (N_EDGES + 255) / 256;        // 6250
    const int NB_SCAN = (N_NODES + 1023) / 1024; // 98
    const int NWB = (N_NODES + 3) / 4;           // 25000
    const int GB = (N_NODES + 127) / 128;        // 782

    k_deg<<<EB, 256, 0, stream>>>(dst, deg);
    k_edge_mlp<<<1024, 256, 0, stream>>>(ea, ew1w, ew1b, ew2w, ew2b, ew);
    k_wpack<<<128, 256, 0, stream>>>(w1l, w1r, W1hi, W1lo);
    k_wpack<<<128, 256, 0, stream>>>(w2l, w2r, W2hi, W2lo);
    k_scan1<<<NB_SCAN, 1024, 0, stream>>>(deg, incl, bsum);
    k_scan2<<<1, 128, 0, stream>>>(bsum, boff, NB_SCAN);
    k_scan3<<<(N_NODES + 255) / 256, 256, 0, stream>>>(incl, boff, rowptr);
    k_fill<<<EB, 256, 0, stream>>>(src, dst, ew, rowptr, cursor, col, wgt);

    // layer 1
    k_agg<<<NWB, 256, 0, stream>>>(x, rowptr, col, wgt, agg);
    k_gemm_mfma<<<GB, 256, 0, stream>>>(agg, x, W1hi, W1lo, b1l,
                                        bn1g, bn1b, bn1m, bn1v, hA);
    // layer 2
    k_agg<<<NWB, 256, 0, stream>>>(hA, rowptr, col, wgt, agg);
    k_gemm_mfma<<<GB, 256, 0, stream>>>(agg, hA, W2hi, W2lo, b2l,
                                        bn2g, bn2b, bn2m, bn2v, hB);
    // layer 3 (transform-then-aggregate: only 2 floats/edge)
    k_lin3<<<NWB, 256, 0, stream>>>(hB, w3l, w3r, t4);
    k_out<<<NWB, 256, 0, stream>>>(t4, rowptr, col, wgt, b3l, out);
}

// Round 4
// 711.162 us; speedup vs baseline: 1.3824x; 1.1195x over previous
//
#include <hip/hip_runtime.h>
#include <math.h>

#define N_NODES 100000
#define N_EDGES 1600000
#define F_INF   128
#define HIDF    128

typedef __attribute__((ext_vector_type(8)))  short short8;
typedef __attribute__((ext_vector_type(16))) float floatx16;

__device__ __forceinline__ unsigned short f2bf(float f) {
    unsigned u = __float_as_uint(f);
    return (unsigned short)((u + 0x7FFFu + ((u >> 16) & 1u)) >> 16);
}

// ---------------------------------------------------------------- edge MLP
// 16 lanes per edge, 4 edges per wave; weights in VGPRs.
__global__ __launch_bounds__(256) void k_edge_mlp(
        const float* __restrict__ ea,
        const float* __restrict__ w1, const float* __restrict__ b1,
        const float* __restrict__ w2, const float* __restrict__ b2,
        float* __restrict__ ew) {
    const int lane = threadIdx.x & 63;
    const int sub  = lane & 15;
    const int grp  = lane >> 4;
    const int wid  = blockIdx.x * (blockDim.x >> 6) + (threadIdx.x >> 6);
    const int nw   = gridDim.x * (blockDim.x >> 6);

    float w1r[8][8], b1r[8], w2r[8];
#pragma unroll
    for (int i = 0; i < 8; ++i) {
        const int h = sub * 8 + i;
#pragma unroll
        for (int k = 0; k < 8; ++k) w1r[k][i] = w1[k * 128 + h];
        b1r[i] = b1[h];
        w2r[i] = w2[h];
    }
    const float bias2 = b2[0];

    for (int e0 = wid * 4; e0 < N_EDGES; e0 += nw * 4) {
        const int e = e0 + grp;
        const float4 a0 = *(const float4*)(ea + (size_t)e * 8);
        const float4 a1 = *(const float4*)(ea + (size_t)e * 8 + 4);
        const float a[8] = {a0.x, a0.y, a0.z, a0.w, a1.x, a1.y, a1.z, a1.w};
        float p = 0.f;
#pragma unroll
        for (int i = 0; i < 8; ++i) {
            float h = b1r[i];
#pragma unroll
            for (int k = 0; k < 8; ++k) h = fmaf(a[k], w1r[k][i], h);
            p = fmaf(fmaxf(h, 0.f), w2r[i], p);
        }
        p += __shfl_xor(p, 1, 64);
        p += __shfl_xor(p, 2, 64);
        p += __shfl_xor(p, 4, 64);
        p += __shfl_xor(p, 8, 64);
        if (sub == 0) {
            const float z = p + bias2;
            ew[e] = 1.f / (1.f + __expf(-z));
        }
    }
}

// ---------------------------------------------------------------- CSR build
__global__ void k_deg(const int* __restrict__ dst, int* __restrict__ deg) {
    int e = blockIdx.x * 256 + threadIdx.x;
    if (e < N_EDGES) atomicAdd(&deg[dst[e]], 1);
}

__global__ void k_scan1(const int* __restrict__ deg, int* __restrict__ incl,
                        int* __restrict__ bsum) {
    __shared__ int sm[1024];
    const int tid = threadIdx.x;
    const int gi  = blockIdx.x * 1024 + tid;
    int v = (gi < N_NODES) ? deg[gi] : 0;
    sm[tid] = v;
    __syncthreads();
    for (int off = 1; off < 1024; off <<= 1) {
        int t = (tid >= off) ? sm[tid - off] : 0;
        __syncthreads();
        sm[tid] += t;
        __syncthreads();
    }
    if (gi < N_NODES) incl[gi] = sm[tid];
    if (tid == 1023) bsum[blockIdx.x] = sm[1023];
}

__global__ void k_scan2(const int* __restrict__ bsum, int* __restrict__ boff, int nb) {
    __shared__ int sm[128];
    const int tid = threadIdx.x;
    int v = (tid < nb) ? bsum[tid] : 0;
    sm[tid] = v;
    __syncthreads();
    for (int off = 1; off < 128; off <<= 1) {
        int t = (tid >= off) ? sm[tid - off] : 0;
        __syncthreads();
        sm[tid] += t;
        __syncthreads();
    }
    boff[tid] = sm[tid] - v;
}

__global__ void k_scan3(const int* __restrict__ incl, const int* __restrict__ boff,
                        int* __restrict__ rowptr) {
    int i = blockIdx.x * 256 + threadIdx.x;
    if (i < N_NODES) rowptr[i + 1] = boff[i >> 10] + incl[i];
    if (i == 0) rowptr[0] = 0;
}

__global__ void k_fill(const int* __restrict__ src, const int* __restrict__ dst,
                       const float* __restrict__ ew, const int* __restrict__ rowptr,
                       int* __restrict__ cursor, int* __restrict__ col,
                       float* __restrict__ wgt) {
    int e = blockIdx.x * 256 + threadIdx.x;
    if (e < N_EDGES) {
        int d   = dst[e];
        int pos = rowptr[d] + atomicAdd(&cursor[d], 1);
        col[pos] = src[e];
        wgt[pos] = ew[e];
    }
}

// ---------------------------------------------------------------- fp32 -> bf16 cast
__global__ void k_cast(const float* __restrict__ x, unsigned short* __restrict__ xb) {
    const int i = (blockIdx.x * 256 + threadIdx.x) * 4;  // N*128 % 4 == 0
    const float4 v = *(const float4*)(x + i);
    ushort4 o;
    o.x = f2bf(v.x); o.y = f2bf(v.y); o.z = f2bf(v.z); o.w = f2bf(v.w);
    *(ushort4*)(xb + i) = o;
}

// ---------------------------------------------------------------- aggregation (bf16 gather)
// wave per node; 32 lanes per edge (lane reads 8 B = 4 bf16), 2 edges per
// wave-instruction, 4-deep unroll => 8 edges in flight. Cross-half reduce at end.
__global__ __launch_bounds__(256) void k_agg16(
        const unsigned short* __restrict__ xb, const int* __restrict__ rowptr,
        const int* __restrict__ col, const float* __restrict__ wgt,
        float* __restrict__ aggout) {
    const int lane = threadIdx.x & 63;
    const int half = lane >> 5;          // which edge of the pair
    const int cl   = lane & 31;          // cols cl*4 .. cl*4+3
    const int node = blockIdx.x * (blockDim.x >> 6) + (threadIdx.x >> 6);
    if (node >= N_NODES) return;
    const int s = rowptr[node], e = rowptr[node + 1];
    float a0 = 0.f, a1 = 0.f, a2 = 0.f, a3 = 0.f;

    for (int j0 = s; j0 < e; j0 += 8) {
        int ss[4]; float ww[4];
#pragma unroll
        for (int u = 0; u < 4; ++u) {
            const int j  = j0 + 2 * u + half;
            const int jc = min(j, e - 1);
            ss[u] = col[jc];
            ww[u] = (j < e) ? wgt[jc] : 0.f;
        }
        uint2 g[4];
#pragma unroll
        for (int u = 0; u < 4; ++u)
            g[u] = *(const uint2*)(xb + (size_t)ss[u] * 128 + cl * 4);
#pragma unroll
        for (int u = 0; u < 4; ++u) {
            const float f0 = __uint_as_float(g[u].x << 16);
            const float f1 = __uint_as_float(g[u].x & 0xFFFF0000u);
            const float f2 = __uint_as_float(g[u].y << 16);
            const float f3 = __uint_as_float(g[u].y & 0xFFFF0000u);
            a0 = fmaf(ww[u], f0, a0);
            a1 = fmaf(ww[u], f1, a1);
            a2 = fmaf(ww[u], f2, a2);
            a3 = fmaf(ww[u], f3, a3);
        }
    }
    a0 += __shfl_xor(a0, 32, 64);
    a1 += __shfl_xor(a1, 32, 64);
    a2 += __shfl_xor(a2, 32, 64);
    a3 += __shfl_xor(a3, 32, 64);
    if (half == 0) {
        const float inv = 1.f / fmaxf((float)(e - s), 1.f);
        float4 r;
        r.x = a0 * inv; r.y = a1 * inv; r.z = a2 * inv; r.w = a3 * inv;
        *(float4*)(aggout + (size_t)node * 128 + cl * 4) = r;
    }
}

// ---------------------------------------------------------------- W packing
// Pack [Wl;Wr] into MFMA B-fragment order (v_mfma_f32_32x32x16_bf16), hi/lo split.
__global__ void k_wpack(const float* __restrict__ Wl, const float* __restrict__ Wr,
                        short* __restrict__ Whi, short* __restrict__ Wlo) {
    int idx = blockIdx.x * 256 + threadIdx.x;   // 32768 total
    int j  = idx & 7;
    int L  = (idx >> 3) & 63;
    int cb = (idx >> 9) & 3;
    int kb = (idx >> 11);
    int k  = kb * 16 + (L >> 5) * 8 + j;
    int n  = cb * 32 + (L & 31);
    float a = (k < 128) ? Wl[k * 128 + n] : Wr[(k - 128) * 128 + n];
    unsigned short hb = f2bf(a);
    float hf = __uint_as_float((unsigned)hb << 16);
    Whi[idx] = (short)hb;
    Wlo[idx] = (short)f2bf(a - hf);
}

// ---------------------------------------------------------------- MFMA GEMM
// h = relu(bn(agg@Wl + b_l + x@Wr)), K=256, split-bf16 (3 MFMA per frag).
// Dual-output epilogue: fp32 `out` + optional bf16 `out16` for next layer's gather.
__global__ __launch_bounds__(256) void k_gemm_mfma(
    const float* __restrict__ Aagg, const float* __restrict__ Ax,
    const short* __restrict__ Whi, const short* __restrict__ Wlo,
    const float* __restrict__ bl,
    const float* __restrict__ bng, const float* __restrict__ bnb,
    const float* __restrict__ bnm, const float* __restrict__ bnv,
    float* __restrict__ out, unsigned short* __restrict__ out16) {
    const int tid  = threadIdx.x;
    const int lane = tid & 63;
    const int w    = tid >> 6;
    const int row0 = blockIdx.x * 128 + w * 32;
    const int rrow = lane & 31;
    const int kq   = lane >> 5;
    const int arow = min(row0 + rrow, N_NODES - 1);

    floatx16 acc[4];
#pragma unroll
    for (int cb = 0; cb < 4; ++cb)
#pragma unroll
        for (int r = 0; r < 16; ++r) acc[cb][r] = 0.f;

    const float* Abase0 = Aagg + (size_t)arow * 128 + kq * 8;
    const float* Abase1 = Ax   + (size_t)arow * 128 + kq * 8;

#pragma unroll 2
    for (int kb = 0; kb < 16; ++kb) {
        const float* ap = ((kb < 8) ? Abase0 : Abase1) + (kb & 7) * 16;
        const float4 a0 = *(const float4*)(ap);
        const float4 a1 = *(const float4*)(ap + 4);
        const float av[8] = {a0.x, a0.y, a0.z, a0.w, a1.x, a1.y, a1.z, a1.w};
        short8 Ah, Al;
#pragma unroll
        for (int j = 0; j < 8; ++j) {
            unsigned short hb = f2bf(av[j]);
            float hf = __uint_as_float((unsigned)hb << 16);
            Ah[j] = (short)hb;
            Al[j] = (short)f2bf(av[j] - hf);
        }
#pragma unroll
        for (int cb = 0; cb < 4; ++cb) {
            const size_t wo = ((size_t)(kb * 4 + cb) * 64 + lane) * 8;
            const short8 wh = *(const short8*)(Whi + wo);
            const short8 wl = *(const short8*)(Wlo + wo);
            acc[cb] = __builtin_amdgcn_mfma_f32_32x32x16_bf16(Ah, wh, acc[cb], 0, 0, 0);
            acc[cb] = __builtin_amdgcn_mfma_f32_32x32x16_bf16(Al, wh, acc[cb], 0, 0, 0);
            acc[cb] = __builtin_amdgcn_mfma_f32_32x32x16_bf16(Ah, wl, acc[cb], 0, 0, 0);
        }
    }

#pragma unroll
    for (int cb = 0; cb < 4; ++cb) {
        const int c = cb * 32 + (lane & 31);
        const float s = bng[c] * rsqrtf(bnv[c] + 1e-5f);
        const float t = (bl[c] - bnm[c]) * s + bnb[c];
#pragma unroll
        for (int r = 0; r < 16; ++r) {
            const int row = row0 + (r & 3) + 8 * (r >> 2) + 4 * kq;
            if (row < N_NODES) {
                const float v = fmaxf(fmaf(acc[cb][r], s, t), 0.f);
                out[(size_t)row * 128 + c] = v;
                if (out16) out16[(size_t)row * 128 + c] = f2bf(v);
            }
        }
    }
}

// ---------------------------------------------------------------- layer 3
__global__ void k_lin3(const float* __restrict__ h, const float* __restrict__ w3l,
                       const float* __restrict__ w3r, float* __restrict__ t4) {
    const int lane = threadIdx.x & 63;
    const int node = blockIdx.x * (blockDim.x >> 6) + (threadIdx.x >> 6);
    if (node >= N_NODES) return;
    float h0 = h[(size_t)node * 128 + lane];
    float h1 = h[(size_t)node * 128 + 64 + lane];
    float2 wl0 = *(const float2*)(w3l + lane * 2);
    float2 wl1 = *(const float2*)(w3l + (64 + lane) * 2);
    float2 wr0 = *(const float2*)(w3r + lane * 2);
    float2 wr1 = *(const float2*)(w3r + (64 + lane) * 2);
    float p0 = h0 * wl0.x + h1 * wl1.x;
    float p1 = h0 * wl0.y + h1 * wl1.y;
    float p2 = h0 * wr0.x + h1 * wr1.x;
    float p3 = h0 * wr0.y + h1 * wr1.y;
#pragma unroll
    for (int m = 1; m < 64; m <<= 1) {
        p0 += __shfl_xor(p0, m, 64);
        p1 += __shfl_xor(p1, m, 64);
        p2 += __shfl_xor(p2, m, 64);
        p3 += __shfl_xor(p3, m, 64);
    }
    if (lane == 0) {
        float4 o; o.x = p0; o.y = p1; o.z = p2; o.w = p3;
        *(float4*)(t4 + (size_t)node * 4) = o;
    }
}

__global__ void k_out(const float* __restrict__ t4, const int* __restrict__ rowptr,
                      const int* __restrict__ col, const float* __restrict__ wgt,
                      const float* __restrict__ b3, float* __restrict__ out) {
    const int lane = threadIdx.x & 63;
    const int node = blockIdx.x * (blockDim.x >> 6) + (threadIdx.x >> 6);
    if (node >= N_NODES) return;
    const int s = rowptr[node], e = rowptr[node + 1];
    float a0 = 0.f, a1 = 0.f;
    for (int j = s + lane; j < e; j += 64) {
        int sr = col[j]; float w = wgt[j];
        float2 t = *(const float2*)(t4 + (size_t)sr * 4);
        a0 += w * t.x; a1 += w * t.y;
    }
#pragma unroll
    for (int m = 1; m < 64; m <<= 1) {
        a0 += __shfl_xor(a0, m, 64);
        a1 += __shfl_xor(a1, m, 64);
    }
    if (lane == 0) {
        float inv = 1.f / fmaxf((float)(e - s), 1.f);
        float2 o;
        o.x = a0 * inv + b3[0] + t4[(size_t)node * 4 + 2];
        o.y = a1 * inv + b3[1] + t4[(size_t)node * 4 + 3];
        *(float2*)(out + (size_t)node * 2) = o;
    }
}

// ---------------------------------------------------------------- launch
extern "C" void kernel_launch(void* const* d_in, const int* in_sizes, int n_in,
                              void* d_out, int out_size, void* d_ws, size_t ws_size,
                              hipStream_t stream) {
    const float* x    = (const float*)d_in[0];
    const float* ea   = (const float*)d_in[1];
    const int*   ei   = (const int*)d_in[2];
    const float* ew1w = (const float*)d_in[3];
    const float* ew1b = (const float*)d_in[4];
    const float* ew2w = (const float*)d_in[5];
    const float* ew2b = (const float*)d_in[6];
    const float* w1l  = (const float*)d_in[7];
    const float* b1l  = (const float*)d_in[8];
    const float* w1r  = (const float*)d_in[9];
    const float* w2l  = (const float*)d_in[10];
    const float* b2l  = (const float*)d_in[11];
    const float* w2r  = (const float*)d_in[12];
    const float* w3l  = (const float*)d_in[13];
    const float* b3l  = (const float*)d_in[14];
    const float* w3r  = (const float*)d_in[15];
    const float* bn1g = (const float*)d_in[16];
    const float* bn1b = (const float*)d_in[17];
    const float* bn1m = (const float*)d_in[18];
    const float* bn1v = (const float*)d_in[19];
    const float* bn2g = (const float*)d_in[20];
    const float* bn2b = (const float*)d_in[21];
    const float* bn2m = (const float*)d_in[22];
    const float* bn2v = (const float*)d_in[23];

    const int* src = ei;
    const int* dst = ei + N_EDGES;
    float* out = (float*)d_out;

    size_t off = 0;
    auto carve = [&](size_t bytes) -> void* {
        void* p = (char*)d_ws + off;
        off += (bytes + 255) & ~(size_t)255;
        return p;
    };
    float* ew     = (float*)carve((size_t)N_EDGES * 4);
    int*   col    = (int*)carve((size_t)N_EDGES * 4);
    float* wgt    = (float*)carve((size_t)N_EDGES * 4);
    int*   rowptr = (int*)carve((size_t)(N_NODES + 1) * 4);
    int*   deg    = (int*)carve((size_t)N_NODES * 4);
    int*   cursor = (int*)carve((size_t)N_NODES * 4);
    int*   bsum   = (int*)carve(128 * 4);
    int*   boff   = (int*)carve(128 * 4);
    int*   incl   = (int*)carve((size_t)N_NODES * 4);
    float* agg    = (float*)carve((size_t)N_NODES * 128 * 4);
    float* hA     = (float*)carve((size_t)N_NODES * 128 * 4);
    float* hB     = (float*)carve((size_t)N_NODES * 128 * 4);
    float* t4     = (float*)carve((size_t)N_NODES * 4 * 4);
    short* W1hi   = (short*)carve(32768 * 2);
    short* W1lo   = (short*)carve(32768 * 2);
    short* W2hi   = (short*)carve(32768 * 2);
    short* W2lo   = (short*)carve(32768 * 2);
    unsigned short* xb   = (unsigned short*)carve((size_t)N_NODES * 128 * 2);
    unsigned short* hA16 = (unsigned short*)carve((size_t)N_NODES * 128 * 2);
    (void)ws_size; (void)n_in; (void)in_sizes; (void)out_size;

    hipMemsetAsync(deg, 0, (size_t)N_NODES * 4, stream);
    hipMemsetAsync(cursor, 0, (size_t)N_NODES * 4, stream);

    const int EB = (N_EDGES + 255) / 256;        // 6250
    const int NB_SCAN = (N_NODES + 1023) / 1024; // 98
    const int NWB = (N_NODES + 3) / 4;           // 25000
    const int GB = (N_NODES + 127) / 128;        // 782
    const int CB = (N_NODES * 128 / 4 + 255) / 256;  // 12500

    k_deg<<<EB, 256, 0, stream>>>(dst, deg);
    k_cast<<<CB, 256, 0, stream>>>(x, xb);
    k_edge_mlp<<<1024, 256, 0, stream>>>(ea, ew1w, ew1b, ew2w, ew2b, ew);
    k_wpack<<<128, 256, 0, stream>>>(w1l, w1r, W1hi, W1lo);
    k_wpack<<<128, 256, 0, stream>>>(w2l, w2r, W2hi, W2lo);
    k_scan1<<<NB_SCAN, 1024, 0, stream>>>(deg, incl, bsum);
    k_scan2<<<1, 128, 0, stream>>>(bsum, boff, NB_SCAN);
    k_scan3<<<(N_NODES + 255) / 256, 256, 0, stream>>>(incl, boff, rowptr);
    k_fill<<<EB, 256, 0, stream>>>(src, dst, ew, rowptr, cursor, col, wgt);

    // layer 1
    k_agg16<<<NWB, 256, 0, stream>>>(xb, rowptr, col, wgt, agg);
    k_gemm_mfma<<<GB, 256, 0, stream>>>(agg, x, W1hi, W1lo, b1l,
                                        bn1g, bn1b, bn1m, bn1v, hA, hA16);
    // layer 2
    k_agg16<<<NWB, 256, 0, stream>>>(hA16, rowptr, col, wgt, agg);
    k_gemm_mfma<<<GB, 256, 0, stream>>>(agg, hA, W2hi, W2lo, b2l,
                                        bn2g, bn2b, bn2m, bn2v, hB, nullptr);
    // layer 3 (transform-then-aggregate: only 2 floats/edge)
    k_lin3<<<NWB, 256, 0, stream>>>(hB, w3l, w3r, t4);
    k_out<<<NWB, 256, 0, stream>>>(t4, rowptr, col, wgt, b3l, out);
}

// Round 5
// 632.203 us; speedup vs baseline: 1.5550x; 1.1249x over previous
//
#include <hip/hip_runtime.h>
#include <math.h>

#define N_NODES 100000
#define N_EDGES 1600000
#define F_INF   128
#define HIDF    128

typedef __attribute__((ext_vector_type(8)))  short short8;
typedef __attribute__((ext_vector_type(16))) float floatx16;

__device__ __forceinline__ unsigned short f2bf(float f) {
    unsigned u = __float_as_uint(f);
    return (unsigned short)((u + 0x7FFFu + ((u >> 16) & 1u)) >> 16);
}

// ---------------------------------------------------------------- edge MLP
// 16 lanes per edge, 4 edges per wave; weights in VGPRs.
__global__ __launch_bounds__(256) void k_edge_mlp(
        const float* __restrict__ ea,
        const float* __restrict__ w1, const float* __restrict__ b1,
        const float* __restrict__ w2, const float* __restrict__ b2,
        float* __restrict__ ew) {
    const int lane = threadIdx.x & 63;
    const int sub  = lane & 15;
    const int grp  = lane >> 4;
    const int wid  = blockIdx.x * (blockDim.x >> 6) + (threadIdx.x >> 6);
    const int nw   = gridDim.x * (blockDim.x >> 6);

    float w1r[8][8], b1r[8], w2r[8];
#pragma unroll
    for (int i = 0; i < 8; ++i) {
        const int h = sub * 8 + i;
#pragma unroll
        for (int k = 0; k < 8; ++k) w1r[k][i] = w1[k * 128 + h];
        b1r[i] = b1[h];
        w2r[i] = w2[h];
    }
    const float bias2 = b2[0];

    for (int e0 = wid * 4; e0 < N_EDGES; e0 += nw * 4) {
        const int e = e0 + grp;
        const float4 a0 = *(const float4*)(ea + (size_t)e * 8);
        const float4 a1 = *(const float4*)(ea + (size_t)e * 8 + 4);
        const float a[8] = {a0.x, a0.y, a0.z, a0.w, a1.x, a1.y, a1.z, a1.w};
        float p = 0.f;
#pragma unroll
        for (int i = 0; i < 8; ++i) {
            float h = b1r[i];
#pragma unroll
            for (int k = 0; k < 8; ++k) h = fmaf(a[k], w1r[k][i], h);
            p = fmaf(fmaxf(h, 0.f), w2r[i], p);
        }
        p += __shfl_xor(p, 1, 64);
        p += __shfl_xor(p, 2, 64);
        p += __shfl_xor(p, 4, 64);
        p += __shfl_xor(p, 8, 64);
        if (sub == 0) {
            const float z = p + bias2;
            ew[e] = 1.f / (1.f + __expf(-z));
        }
    }
}

// ---------------------------------------------------------------- CSR build
// k_deg: degree histogram + per-edge rank (order within its dst's slot range).
__global__ void k_deg(const int* __restrict__ dst, int* __restrict__ deg,
                      unsigned char* __restrict__ rank) {
    int e = blockIdx.x * 256 + threadIdx.x;
    if (e < N_EDGES) rank[e] = (unsigned char)atomicAdd(&deg[dst[e]], 1);
}

__global__ void k_scan1(const int* __restrict__ deg, int* __restrict__ incl,
                        int* __restrict__ bsum) {
    __shared__ int sm[1024];
    const int tid = threadIdx.x;
    const int gi  = blockIdx.x * 1024 + tid;
    int v = (gi < N_NODES) ? deg[gi] : 0;
    sm[tid] = v;
    __syncthreads();
    for (int off = 1; off < 1024; off <<= 1) {
        int t = (tid >= off) ? sm[tid - off] : 0;
        __syncthreads();
        sm[tid] += t;
        __syncthreads();
    }
    if (gi < N_NODES) incl[gi] = sm[tid];
    if (tid == 1023) bsum[blockIdx.x] = sm[1023];
}

__global__ void k_scan2(const int* __restrict__ bsum, int* __restrict__ boff, int nb) {
    __shared__ int sm[128];
    const int tid = threadIdx.x;
    int v = (tid < nb) ? bsum[tid] : 0;
    sm[tid] = v;
    __syncthreads();
    for (int off = 1; off < 128; off <<= 1) {
        int t = (tid >= off) ? sm[tid - off] : 0;
        __syncthreads();
        sm[tid] += t;
        __syncthreads();
    }
    boff[tid] = sm[tid] - v;
}

__global__ void k_scan3(const int* __restrict__ incl, const int* __restrict__ boff,
                        int* __restrict__ rowptr) {
    int i = blockIdx.x * 256 + threadIdx.x;
    if (i < N_NODES) rowptr[i + 1] = boff[i >> 10] + incl[i];
    if (i == 0) rowptr[0] = 0;
}

// k_fill: single 4B packed scatter per edge: (src:17 bits << 15) | bf16(ew)>>1
// (ew = sigmoid > 0 so its bf16 sign bit is 0 -> 15 bits suffice). No atomics.
__global__ void k_fill(const int* __restrict__ src, const int* __restrict__ dst,
                       const float* __restrict__ ew, const int* __restrict__ rowptr,
                       const unsigned char* __restrict__ rank,
                       unsigned* __restrict__ cw) {
    int e = blockIdx.x * 256 + threadIdx.x;
    if (e < N_EDGES) {
        int d   = dst[e];
        int pos = rowptr[d] + (int)rank[e];
        unsigned wb = (unsigned)f2bf(ew[e]) & 0x7FFFu;
        cw[pos] = ((unsigned)src[e] << 15) | wb;
    }
}

// ---------------------------------------------------------------- fp32 -> bf16 cast
__global__ void k_cast(const float* __restrict__ x, unsigned short* __restrict__ xb) {
    const int i = (blockIdx.x * 256 + threadIdx.x) * 4;  // N*128 % 4 == 0
    const float4 v = *(const float4*)(x + i);
    ushort4 o;
    o.x = f2bf(v.x); o.y = f2bf(v.y); o.z = f2bf(v.z); o.w = f2bf(v.w);
    *(ushort4*)(xb + i) = o;
}

// ---------------------------------------------------------------- aggregation (bf16 gather)
// wave per node; 32 lanes per edge (lane reads 8 B = 4 bf16), 2 edges per
// wave-instruction, 4-deep unroll => 8 edges in flight. Cross-half reduce at end.
__global__ __launch_bounds__(256) void k_agg16(
        const unsigned short* __restrict__ xb, const int* __restrict__ rowptr,
        const unsigned* __restrict__ cw, float* __restrict__ aggout) {
    const int lane = threadIdx.x & 63;
    const int half = lane >> 5;          // which edge of the pair
    const int cl   = lane & 31;          // cols cl*4 .. cl*4+3
    const int node = blockIdx.x * (blockDim.x >> 6) + (threadIdx.x >> 6);
    if (node >= N_NODES) return;
    const int s = rowptr[node], e = rowptr[node + 1];
    float a0 = 0.f, a1 = 0.f, a2 = 0.f, a3 = 0.f;

    for (int j0 = s; j0 < e; j0 += 8) {
        int ss[4]; float ww[4];
#pragma unroll
        for (int u = 0; u < 4; ++u) {
            const int j  = j0 + 2 * u + half;
            const int jc = min(j, e - 1);
            const unsigned p = cw[jc];
            ss[u] = (int)(p >> 15);
            ww[u] = (j < e) ? __uint_as_float((p & 0x7FFFu) << 16) : 0.f;
        }
        uint2 g[4];
#pragma unroll
        for (int u = 0; u < 4; ++u)
            g[u] = *(const uint2*)(xb + (size_t)ss[u] * 128 + cl * 4);
#pragma unroll
        for (int u = 0; u < 4; ++u) {
            const float f0 = __uint_as_float(g[u].x << 16);
            const float f1 = __uint_as_float(g[u].x & 0xFFFF0000u);
            const float f2 = __uint_as_float(g[u].y << 16);
            const float f3 = __uint_as_float(g[u].y & 0xFFFF0000u);
            a0 = fmaf(ww[u], f0, a0);
            a1 = fmaf(ww[u], f1, a1);
            a2 = fmaf(ww[u], f2, a2);
            a3 = fmaf(ww[u], f3, a3);
        }
    }
    a0 += __shfl_xor(a0, 32, 64);
    a1 += __shfl_xor(a1, 32, 64);
    a2 += __shfl_xor(a2, 32, 64);
    a3 += __shfl_xor(a3, 32, 64);
    if (half == 0) {
        const float inv = 1.f / fmaxf((float)(e - s), 1.f);
        float4 r;
        r.x = a0 * inv; r.y = a1 * inv; r.z = a2 * inv; r.w = a3 * inv;
        *(float4*)(aggout + (size_t)node * 128 + cl * 4) = r;
    }
}

// ---------------------------------------------------------------- W packing
// Pack [Wl;Wr] into MFMA B-fragment order (v_mfma_f32_32x32x16_bf16), hi/lo split.
__global__ void k_wpack(const float* __restrict__ Wl, const float* __restrict__ Wr,
                        short* __restrict__ Whi, short* __restrict__ Wlo) {
    int idx = blockIdx.x * 256 + threadIdx.x;   // 32768 total
    int j  = idx & 7;
    int L  = (idx >> 3) & 63;
    int cb = (idx >> 9) & 3;
    int kb = (idx >> 11);
    int k  = kb * 16 + (L >> 5) * 8 + j;
    int n  = cb * 32 + (L & 31);
    float a = (k < 128) ? Wl[k * 128 + n] : Wr[(k - 128) * 128 + n];
    unsigned short hb = f2bf(a);
    float hf = __uint_as_float((unsigned)hb << 16);
    Whi[idx] = (short)hb;
    Wlo[idx] = (short)f2bf(a - hf);
}

// ---------------------------------------------------------------- MFMA GEMM
// h = relu(bn(agg@Wl + b_l + x@Wr)), K=256, split-bf16 (3 MFMA per frag).
// Dual-output epilogue: fp32 `out` + optional bf16 `out16` for next layer's gather.
__global__ __launch_bounds__(256) void k_gemm_mfma(
    const float* __restrict__ Aagg, const float* __restrict__ Ax,
    const short* __restrict__ Whi, const short* __restrict__ Wlo,
    const float* __restrict__ bl,
    const float* __restrict__ bng, const float* __restrict__ bnb,
    const float* __restrict__ bnm, const float* __restrict__ bnv,
    float* __restrict__ out, unsigned short* __restrict__ out16) {
    const int tid  = threadIdx.x;
    const int lane = tid & 63;
    const int w    = tid >> 6;
    const int row0 = blockIdx.x * 128 + w * 32;
    const int rrow = lane & 31;
    const int kq   = lane >> 5;
    const int arow = min(row0 + rrow, N_NODES - 1);

    floatx16 acc[4];
#pragma unroll
    for (int cb = 0; cb < 4; ++cb)
#pragma unroll
        for (int r = 0; r < 16; ++r) acc[cb][r] = 0.f;

    const float* Abase0 = Aagg + (size_t)arow * 128 + kq * 8;
    const float* Abase1 = Ax   + (size_t)arow * 128 + kq * 8;

#pragma unroll 2
    for (int kb = 0; kb < 16; ++kb) {
        const float* ap = ((kb < 8) ? Abase0 : Abase1) + (kb & 7) * 16;
        const float4 a0 = *(const float4*)(ap);
        const float4 a1 = *(const float4*)(ap + 4);
        const float av[8] = {a0.x, a0.y, a0.z, a0.w, a1.x, a1.y, a1.z, a1.w};
        short8 Ah, Al;
#pragma unroll
        for (int j = 0; j < 8; ++j) {
            unsigned short hb = f2bf(av[j]);
            float hf = __uint_as_float((unsigned)hb << 16);
            Ah[j] = (short)hb;
            Al[j] = (short)f2bf(av[j] - hf);
        }
#pragma unroll
        for (int cb = 0; cb < 4; ++cb) {
            const size_t wo = ((size_t)(kb * 4 + cb) * 64 + lane) * 8;
            const short8 wh = *(const short8*)(Whi + wo);
            const short8 wl = *(const short8*)(Wlo + wo);
            acc[cb] = __builtin_amdgcn_mfma_f32_32x32x16_bf16(Ah, wh, acc[cb], 0, 0, 0);
            acc[cb] = __builtin_amdgcn_mfma_f32_32x32x16_bf16(Al, wh, acc[cb], 0, 0, 0);
            acc[cb] = __builtin_amdgcn_mfma_f32_32x32x16_bf16(Ah, wl, acc[cb], 0, 0, 0);
        }
    }

#pragma unroll
    for (int cb = 0; cb < 4; ++cb) {
        const int c = cb * 32 + (lane & 31);
        const float s = bng[c] * rsqrtf(bnv[c] + 1e-5f);
        const float t = (bl[c] - bnm[c]) * s + bnb[c];
#pragma unroll
        for (int r = 0; r < 16; ++r) {
            const int row = row0 + (r & 3) + 8 * (r >> 2) + 4 * kq;
            if (row < N_NODES) {
                const float v = fmaxf(fmaf(acc[cb][r], s, t), 0.f);
                out[(size_t)row * 128 + c] = v;
                if (out16) out16[(size_t)row * 128 + c] = f2bf(v);
            }
        }
    }
}

// ---------------------------------------------------------------- layer 3
__global__ void k_lin3(const float* __restrict__ h, const float* __restrict__ w3l,
                       const float* __restrict__ w3r, float* __restrict__ t4) {
    const int lane = threadIdx.x & 63;
    const int node = blockIdx.x * (blockDim.x >> 6) + (threadIdx.x >> 6);
    if (node >= N_NODES) return;
    float h0 = h[(size_t)node * 128 + lane];
    float h1 = h[(size_t)node * 128 + 64 + lane];
    float2 wl0 = *(const float2*)(w3l + lane * 2);
    float2 wl1 = *(const float2*)(w3l + (64 + lane) * 2);
    float2 wr0 = *(const float2*)(w3r + lane * 2);
    float2 wr1 = *(const float2*)(w3r + (64 + lane) * 2);
    float p0 = h0 * wl0.x + h1 * wl1.x;
    float p1 = h0 * wl0.y + h1 * wl1.y;
    float p2 = h0 * wr0.x + h1 * wr1.x;
    float p3 = h0 * wr0.y + h1 * wr1.y;
#pragma unroll
    for (int m = 1; m < 64; m <<= 1) {
        p0 += __shfl_xor(p0, m, 64);
        p1 += __shfl_xor(p1, m, 64);
        p2 += __shfl_xor(p2, m, 64);
        p3 += __shfl_xor(p3, m, 64);
    }
    if (lane == 0) {
        float4 o; o.x = p0; o.y = p1; o.z = p2; o.w = p3;
        *(float4*)(t4 + (size_t)node * 4) = o;
    }
}

__global__ void k_out(const float* __restrict__ t4, const int* __restrict__ rowptr,
                      const unsigned* __restrict__ cw,
                      const float* __restrict__ b3, float* __restrict__ out) {
    const int lane = threadIdx.x & 63;
    const int node = blockIdx.x * (blockDim.x >> 6) + (threadIdx.x >> 6);
    if (node >= N_NODES) return;
    const int s = rowptr[node], e = rowptr[node + 1];
    float a0 = 0.f, a1 = 0.f;
    for (int j = s + lane; j < e; j += 64) {
        const unsigned p = cw[j];
        const int   sr = (int)(p >> 15);
        const float w  = __uint_as_float((p & 0x7FFFu) << 16);
        float2 t = *(const float2*)(t4 + (size_t)sr * 4);
        a0 += w * t.x; a1 += w * t.y;
    }
#pragma unroll
    for (int m = 1; m < 64; m <<= 1) {
        a0 += __shfl_xor(a0, m, 64);
        a1 += __shfl_xor(a1, m, 64);
    }
    if (lane == 0) {
        float inv = 1.f / fmaxf((float)(e - s), 1.f);
        float2 o;
        o.x = a0 * inv + b3[0] + t4[(size_t)node * 4 + 2];
        o.y = a1 * inv + b3[1] + t4[(size_t)node * 4 + 3];
        *(float2*)(out + (size_t)node * 2) = o;
    }
}

// ---------------------------------------------------------------- launch
extern "C" void kernel_launch(void* const* d_in, const int* in_sizes, int n_in,
                              void* d_out, int out_size, void* d_ws, size_t ws_size,
                              hipStream_t stream) {
    const float* x    = (const float*)d_in[0];
    const float* ea   = (const float*)d_in[1];
    const int*   ei   = (const int*)d_in[2];
    const float* ew1w = (const float*)d_in[3];
    const float* ew1b = (const float*)d_in[4];
    const float* ew2w = (const float*)d_in[5];
    const float* ew2b = (const float*)d_in[6];
    const float* w1l  = (const float*)d_in[7];
    const float* b1l  = (const float*)d_in[8];
    const float* w1r  = (const float*)d_in[9];
    const float* w2l  = (const float*)d_in[10];
    const float* b2l  = (const float*)d_in[11];
    const float* w2r  = (const float*)d_in[12];
    const float* w3l  = (const float*)d_in[13];
    const float* b3l  = (const float*)d_in[14];
    const float* w3r  = (const float*)d_in[15];
    const float* bn1g = (const float*)d_in[16];
    const float* bn1b = (const float*)d_in[17];
    const float* bn1m = (const float*)d_in[18];
    const float* bn1v = (const float*)d_in[19];
    const float* bn2g = (const float*)d_in[20];
    const float* bn2b = (const float*)d_in[21];
    const float* bn2m = (const float*)d_in[22];
    const float* bn2v = (const float*)d_in[23];

    const int* src = ei;
    const int* dst = ei + N_EDGES;
    float* out = (float*)d_out;

    size_t off = 0;
    auto carve = [&](size_t bytes) -> void* {
        void* p = (char*)d_ws + off;
        off += (bytes + 255) & ~(size_t)255;
        return p;
    };
    float* ew     = (float*)carve((size_t)N_EDGES * 4);
    unsigned* cw  = (unsigned*)carve((size_t)N_EDGES * 4);
    unsigned char* rank = (unsigned char*)carve((size_t)N_EDGES);
    int*   rowptr = (int*)carve((size_t)(N_NODES + 1) * 4);
    int*   deg    = (int*)carve((size_t)N_NODES * 4);
    int*   bsum   = (int*)carve(128 * 4);
    int*   boff   = (int*)carve(128 * 4);
    int*   incl   = (int*)carve((size_t)N_NODES * 4);
    float* agg    = (float*)carve((size_t)N_NODES * 128 * 4);
    float* hA     = (float*)carve((size_t)N_NODES * 128 * 4);
    float* hB     = (float*)carve((size_t)N_NODES * 128 * 4);
    float* t4     = (float*)carve((size_t)N_NODES * 4 * 4);
    short* W1hi   = (short*)carve(32768 * 2);
    short* W1lo   = (short*)carve(32768 * 2);
    short* W2hi   = (short*)carve(32768 * 2);
    short* W2lo   = (short*)carve(32768 * 2);
    unsigned short* xb   = (unsigned short*)carve((size_t)N_NODES * 128 * 2);
    unsigned short* hA16 = (unsigned short*)carve((size_t)N_NODES * 128 * 2);
    (void)ws_size; (void)n_in; (void)in_sizes; (void)out_size;

    hipMemsetAsync(deg, 0, (size_t)N_NODES * 4, stream);

    const int EB = (N_EDGES + 255) / 256;        // 6250
    const int NB_SCAN = (N_NODES + 1023) / 1024; // 98
    const int NWB = (N_NODES + 3) / 4;           // 25000
    const int GB = (N_NODES + 127) / 128;        // 782
    const int CB = (N_NODES * 128 / 4 + 255) / 256;  // 12500

    k_deg<<<EB, 256, 0, stream>>>(dst, deg, rank);
    k_cast<<<CB, 256, 0, stream>>>(x, xb);
    k_edge_mlp<<<1024, 256, 0, stream>>>(ea, ew1w, ew1b, ew2w, ew2b, ew);
    k_wpack<<<128, 256, 0, stream>>>(w1l, w1r, W1hi, W1lo);
    k_wpack<<<128, 256, 0, stream>>>(w2l, w2r, W2hi, W2lo);
    k_scan1<<<NB_SCAN, 1024, 0, stream>>>(deg, incl, bsum);
    k_scan2<<<1, 128, 0, stream>>>(bsum, boff, NB_SCAN);
    k_scan3<<<(N_NODES + 255) / 256, 256, 0, stream>>>(incl, boff, rowptr);
    k_fill<<<EB, 256, 0, stream>>>(src, dst, ew, rowptr, rank, cw);

    // layer 1
    k_agg16<<<NWB, 256, 0, stream>>>(xb, rowptr, cw, agg);
    k_gemm_mfma<<<GB, 256, 0, stream>>>(agg, x, W1hi, W1lo, b1l,
                                        bn1g, bn1b, bn1m, bn1v, hA, hA16);
    // layer 2
    k_agg16<<<NWB, 256, 0, stream>>>(hA16, rowptr, cw, agg);
    k_gemm_mfma<<<GB, 256, 0, stream>>>(agg, hA, W2hi, W2lo, b2l,
                                        bn2g, bn2b, bn2m, bn2v, hB, nullptr);
    // layer 3 (transform-then-aggregate: only 2 floats/edge)
    k_lin3<<<NWB, 256, 0, stream>>>(hB, w3l, w3r, t4);
    k_out<<<NWB, 256, 0, stream>>>(t4, rowptr, cw, b3l, out);
}